// Round 11
// baseline (3778.422 us; speedup 1.0000x reference)
//
#include <hip/hip_runtime.h>
#include <stdint.h>

typedef unsigned long long u64;
typedef double v4d __attribute__((ext_vector_type(4)));

#define NIMG 8
#define CIN 512
#define COUT 512
#define NPOS 4096            // 64*64
#define NSC 36864            // 9*64*64
#define PRE_TOPN 3000
#define POST_TOPN 300
#define NWORDS 47            // ceil(3000/64)
#define MSTRIDE 48           // padded words per mask row
#define WROW 66              // padded W row (doubles); 33 x 16B units
#define WCH_DBL 2376         // 36*66 doubles per chunk
#define WBUF_BYTES 19008     // 36*66*8
#define XBUF 1088            // 4ci * 4rows * 68 f32 per chunk

__constant__ double dANC[9][4] = {
    {-83.0, -39.0, 100.0, 56.0},   {-175.0, -87.0, 192.0, 104.0},
    {-359.0, -183.0, 376.0, 200.0},{-55.0, -55.0, 72.0, 72.0},
    {-119.0, -119.0, 136.0, 136.0},{-247.0, -247.0, 264.0, 264.0},
    {-35.0, -79.0, 52.0, 96.0},    {-79.0, -167.0, 96.0, 184.0},
    {-167.0, -343.0, 184.0, 360.0}};

static __device__ __forceinline__ void gload16(const void* g, void* l) {
    __builtin_amdgcn_global_load_lds(
        (const __attribute__((address_space(1))) void*)g,
        (__attribute__((address_space(3))) void*)l, 16, 0, 0);
}

// ---- W transpose+cvt: W_conv [512oc][4608k] -> Wtd2 [8 octile][4608k][66] f64 (64 + 2 pad)
__global__ __launch_bounds__(256) void transpose_wconv_f64(const float* __restrict__ W,
                                                           double* __restrict__ Wtd2) {
    __shared__ float t[32][33];
    int k0 = blockIdx.x * 32;
    int o0 = blockIdx.y * 32;
    int tid = threadIdx.x;
    for (int idx = tid; idx < 1024; idx += 256) {
        int r = idx >> 5, c = idx & 31;
        t[r][c] = W[(size_t)(o0 + r) * 4608 + k0 + c];
    }
    __syncthreads();
    for (int idx = tid; idx < 1024; idx += 256) {
        int r = idx >> 5, c = idx & 31;
        int oc = o0 + c;
        Wtd2[((size_t)(oc >> 6) * 4608 + (k0 + r)) * WROW + (oc & 63)] = (double)t[c][r];
    }
}

// ---- heads W: Wh [512k][64o]  (o<36: W_reg, 36..53: W_cls, rest 0)
__global__ __launch_bounds__(256) void build_wheads(const float* __restrict__ Wreg,
                                                    const float* __restrict__ Wcls,
                                                    float* __restrict__ Wh) {
    int g = blockIdx.x * 256 + threadIdx.x;
    if (g >= 512 * 64) return;
    int k = g >> 6, o = g & 63;
    float v = 0.f;
    if (o < 36) v = Wreg[o * 512 + k];
    else if (o < 54) v = Wcls[(o - 36) * 512 + k];
    Wh[g] = v;
}

// ---- MFMA layout probe: MFMA chain vs exact int reference (verified HW layout -> variant)
__global__ __launch_bounds__(64) void mfma_probe(int* __restrict__ variant) {
    __shared__ double AA[72][16];   // [K][m] : A[m][K] = m*73 + K + 1
    __shared__ double BB[72][16];   // [K][n] : B[K][n] = K*17 + 3n + 1
    const int L = threadIdx.x;
    for (int i = L; i < 72 * 16; i += 64) {
        int K = i >> 4, c = i & 15;
        AA[K][c] = (double)(c * 73 + K + 1);
        BB[K][c] = (double)(K * 17 + 3 * c + 1);
    }
    __syncthreads();
    const int lg = L >> 4, lm = L & 15;
    v4d accN = {0.0, 0.0, 0.0, 0.0};
    v4d accS = {0.0, 0.0, 0.0, 0.0};
#pragma unroll
    for (int k4 = 0; k4 < 18; ++k4) {
        double a = AA[4 * k4 + lg][lm];
        double b = BB[4 * k4 + lg][lm];
        accN = __builtin_amdgcn_mfma_f64_16x16x4f64(a, b, accN, 0, 0, 0);
        accS = __builtin_amdgcn_mfma_f64_16x16x4f64(b, a, accS, 0, 0, 0);
    }
    int found = 255;
    for (int v = 0; v < 8; ++v) {
        bool ok = true;
        for (int r = 0; r < 4; ++r) {
            int m, n;
            int dm = v & 3;
            if (dm == 0)      { m = 4 * lg + r; n = lm; }
            else if (dm == 1) { m = lm; n = 4 * lg + r; }
            else if (dm == 2) { m = lg + 4 * r; n = lm; }
            else              { m = lm; n = lg + 4 * r; }
            long long ref = 0;
            for (int K = 0; K < 72; ++K)
                ref += (long long)(m * 73 + K + 1) * (long long)(K * 17 + 3 * n + 1);
            double got = (v < 4) ? accN[r] : accS[r];
            ok = ok && (got == (double)ref);
        }
        if (__all(ok) && found == 255) found = v;
    }
    if (L == 0) *variant = found;
}

// ---- conv 3x3 SAME via f64 MFMA; 8 waves/block; wave = 32oc x 32pos (2x2 frags);
// block = 64oc x 2 y-rows x 64pos. W: gload_lds dbuf (f64); X: f32 LDS, cvt at read.
__global__ __launch_bounds__(512) void conv_mfma(const float* __restrict__ X,
                                                 const double* __restrict__ Wtd2,
                                                 const float* __restrict__ bconv,
                                                 double* __restrict__ convb,
                                                 const int* __restrict__ variant,
                                                 int img_base) {
    const int vr = *variant;
    if (vr > 7) return;
    const int tid = threadIdx.x;
    const int wv = tid >> 6;        // 0..7
    const int lane = tid & 63;
    const int lg = lane >> 4;
    const int lm = lane & 15;
    const int ocg = wv & 1;         // 32-oc half
    const int yh = (wv >> 1) & 1;   // y row within the pair
    const int ph = wv >> 2;         // pos half (0/1 -> 32)
    const int octile = blockIdx.x;
    const int oc0 = octile * 64;
    const int y0 = blockIdx.y * 2;
    const int imgL = blockIdx.z;
    const int img_g = img_base + imgL;

    __shared__ double Wl[2][36][WROW];   // A panel (38016 B)
    __shared__ float Xl[2][4][4][68];    // B panel: 4ci x rows y0-1..y0+2 (8704 B)
    char* wl0 = (char*)&Wl[0][0][0];
    float* xl0 = &Xl[0][0][0][0];

    v4d acc[2][2];
#pragma unroll
    for (int oq = 0; oq < 2; ++oq)
#pragma unroll
        for (int pq = 0; pq < 2; ++pq) acc[oq][pq] = (v4d){0.0, 0.0, 0.0, 0.0};

    // B row offsets for the 9 K4-steps of a 4-ci chunk (flat k = c*9 + ty*3 + tx)
    int boff[9];
#pragma unroll
    for (int k4 = 0; k4 < 9; ++k4) {
        int row = k4 * 4 + lg;
        int c = row / 9;
        int t = row - 9 * c;
        int ty = t / 3;
        int tx = t - 3 * ty;
        boff[k4] = (c * 4 + yh + ty) * 68 + tx + ph * 32 + lm;
    }

    // X staging: 1088 f32/chunk; slots tid, tid+512, (tid<64) tid+1024
    int xoff0, xoff1, xoff2;
    {
        int idx = tid;
        int c_l = idx / 272;
        int rem = idx - c_l * 272;
        int r = rem / 68;
        int xx = rem - r * 68;
        int yy = y0 + r - 1;
        int xg = xx - 1;
        xoff0 = (xx < 66 && (unsigned)yy < 64u && (unsigned)xg < 64u)
                    ? ((img_g * CIN + c_l) * 64 + yy) * 64 + xg : -1;
    }
    {
        int idx = 512 + tid;
        int c_l = idx / 272;
        int rem = idx - c_l * 272;
        int r = rem / 68;
        int xx = rem - r * 68;
        int yy = y0 + r - 1;
        int xg = xx - 1;
        xoff1 = (xx < 66 && (unsigned)yy < 64u && (unsigned)xg < 64u)
                    ? ((img_g * CIN + c_l) * 64 + yy) * 64 + xg : -1;
    }
    xoff2 = -1;
    if (tid < 64) {
        int idx = 1024 + tid;
        int c_l = idx / 272;
        int rem = idx - c_l * 272;
        int r = rem / 68;
        int xx = rem - r * 68;
        int yy = y0 + r - 1;
        int xg = xx - 1;
        if (xx < 66 && (unsigned)yy < 64u && (unsigned)xg < 64u)
            xoff2 = ((img_g * CIN + c_l) * 64 + yy) * 64 + xg;
    }
    // W DMA descriptors: 1188 16B-units/chunk; 2 full rounds + 164-unit reg remainder
    int woff[2];
#pragma unroll
    for (int i = 0; i < 2; ++i) {
        int u = i * 512 + tid;
        int row = u / 33, cp = u - 33 * row;
        woff[i] = (octile * 4608 + row) * WROW + cp * 2;
    }
    int woff4;
    {
        int u = 1024 + tid;
        int row = u / 33, cp = u - 33 * row;
        woff4 = (octile * 4608 + row) * WROW + cp * 2;
    }

    float xr0, xr1, xr2;
    double2 wrr;

#define WDMA(c, par) { \
    gload16(&Wtd2[(size_t)woff[0] + (size_t)(c) * WCH_DBL], \
            wl0 + (size_t)(par) * WBUF_BYTES + (size_t)tid * 16); \
    gload16(&Wtd2[(size_t)woff[1] + (size_t)(c) * WCH_DBL], \
            wl0 + (size_t)(par) * WBUF_BYTES + (size_t)(512 + tid) * 16); }

#define LOADR(c) { \
    if (tid < 164) wrr = *(const double2*)&Wtd2[(size_t)woff4 + (size_t)(c) * WCH_DBL]; \
    xr0 = (xoff0 >= 0) ? X[(size_t)xoff0 + (size_t)(c) * 16384] : 0.f; \
    xr1 = (xoff1 >= 0) ? X[(size_t)xoff1 + (size_t)(c) * 16384] : 0.f; \
    xr2 = (xoff2 >= 0) ? X[(size_t)xoff2 + (size_t)(c) * 16384] : 0.f; }

#define WRITER(par) { \
    if (tid < 164) \
        *(double2*)(wl0 + (size_t)(par) * WBUF_BYTES + (size_t)(1024 + tid) * 16) = wrr; \
    xl0[(size_t)(par) * XBUF + tid] = xr0; \
    xl0[(size_t)(par) * XBUF + 512 + tid] = xr1; \
    if (tid < 64) xl0[(size_t)(par) * XBUF + 1024 + tid] = xr2; }

    // prologue: stage chunk 0 into buffer 0
    WDMA(0, 0);
    LOADR(0);
    WRITER(0);
    __syncthreads();   // drains DMA (vmcnt 0) + makes writes visible

    const bool swapped = (vr >= 4);
    const int aoff0 = ocg * 32 + lm;

    for (int c = 0; c < 128; ++c) {
        const int par = c & 1;
        if (c < 127) { WDMA(c + 1, par ^ 1); LOADR(c + 1); }   // async, fly under MFMA
        const double* wb = &Wl[par][0][0];
        const float* bx = xl0 + (size_t)par * XBUF;
        if (!swapped) {
#pragma unroll
            for (int k4 = 0; k4 < 9; ++k4) {
                const double* wp = wb + (4 * k4 + lg) * WROW + aoff0;
                double a0 = wp[0];
                double a1 = wp[16];
                const float* bp = bx + boff[k4];
                double b0 = (double)bp[0];
                double b1 = (double)bp[16];
                acc[0][0] = __builtin_amdgcn_mfma_f64_16x16x4f64(a0, b0, acc[0][0], 0, 0, 0);
                acc[0][1] = __builtin_amdgcn_mfma_f64_16x16x4f64(a0, b1, acc[0][1], 0, 0, 0);
                acc[1][0] = __builtin_amdgcn_mfma_f64_16x16x4f64(a1, b0, acc[1][0], 0, 0, 0);
                acc[1][1] = __builtin_amdgcn_mfma_f64_16x16x4f64(a1, b1, acc[1][1], 0, 0, 0);
            }
        } else {
#pragma unroll
            for (int k4 = 0; k4 < 9; ++k4) {
                const double* wp = wb + (4 * k4 + lg) * WROW + aoff0;
                double a0 = wp[0];
                double a1 = wp[16];
                const float* bp = bx + boff[k4];
                double b0 = (double)bp[0];
                double b1 = (double)bp[16];
                acc[0][0] = __builtin_amdgcn_mfma_f64_16x16x4f64(b0, a0, acc[0][0], 0, 0, 0);
                acc[0][1] = __builtin_amdgcn_mfma_f64_16x16x4f64(b1, a0, acc[0][1], 0, 0, 0);
                acc[1][0] = __builtin_amdgcn_mfma_f64_16x16x4f64(b0, a1, acc[1][0], 0, 0, 0);
                acc[1][1] = __builtin_amdgcn_mfma_f64_16x16x4f64(b1, a1, acc[1][1], 0, 0, 0);
            }
        }
        if (c < 127) { WRITER(par ^ 1); }   // xr/wrr waits land here, post-compute
        __syncthreads();
    }
#undef WDMA
#undef LOADR
#undef WRITER

    // epilogue via verified variant decode
    const int dm = vr & 3;
    const int yrow = y0 + yh;
#pragma unroll
    for (int oq = 0; oq < 2; ++oq) {
#pragma unroll
        for (int pq = 0; pq < 2; ++pq) {
#pragma unroll
            for (int r = 0; r < 4; ++r) {
                int m, n;
                if (dm == 0)      { m = 4 * lg + r; n = lm; }
                else if (dm == 1) { m = lm; n = 4 * lg + r; }
                else if (dm == 2) { m = lg + 4 * r; n = lm; }
                else              { m = lm; n = lg + 4 * r; }
                int oc = oc0 + ocg * 32 + oq * 16 + m;
                int xp = ph * 32 + pq * 16 + n;
                convb[((size_t)imgL * COUT + oc) * NPOS + yrow * 64 + xp] =
                    acc[oq][pq][r] + (double)bconv[oc];
            }
        }
    }
}

// ---- conv 3x3 SAME, fp64 VALU fallback (runs only if probe found no variant)
__global__ __launch_bounds__(256) void conv_valu(const float* __restrict__ X,
                                                 const double* __restrict__ Wtd2,
                                                 const float* __restrict__ bconv,
                                                 double* __restrict__ convb,
                                                 const int* __restrict__ variant,
                                                 int img_base) {
    if (*variant <= 7) return;
    const int tid = threadIdx.x;
    const int octile = blockIdx.x;
    const int oc0 = octile * 64;
    const int y = blockIdx.y;
    const int imgL = blockIdx.z;
    const int img_g = img_base + imgL;
    const int x_l = (tid & 15) * 4;
    const int oc_l = (tid >> 4) * 4;

    __shared__ double Wl[72][64];
    __shared__ double Bx[8][3][68];

    double acc[4][4];
#pragma unroll
    for (int i = 0; i < 4; ++i)
#pragma unroll
        for (int j = 0; j < 4; ++j) acc[i][j] = 0.0;

    for (int cc = 0; cc < CIN; cc += 8) {
        __syncthreads();
        for (int idx = tid; idx < 8 * 3 * 68; idx += 256) {
            int c_l = idx / 204;
            int rem = idx - c_l * 204;
            int r = rem / 68;
            int xx = rem - r * 68;
            int yy = y + r - 1;
            int xg = xx - 1;
            float v = 0.f;
            if (xx < 66 && (unsigned)yy < 64u && (unsigned)xg < 64u)
                v = X[(((size_t)img_g * CIN + cc + c_l) * 64 + yy) * 64 + xg];
            Bx[c_l][r][xx] = (double)v;
        }
        for (int idx = tid; idx < 72 * 32; idx += 256) {
            int kl = idx >> 5, cp = idx & 31;
            double2 v = *(const double2*)&Wtd2[((size_t)octile * 4608 + cc * 9 + kl) * WROW + cp * 2];
            *(double2*)&Wl[kl][cp * 2] = v;
        }
        __syncthreads();
#pragma unroll 2
        for (int c_l = 0; c_l < 8; ++c_l) {
#pragma unroll
            for (int ty = 0; ty < 3; ++ty) {
                double xv[6];
                *(double2*)&xv[0] = *(const double2*)&Bx[c_l][ty][x_l + 0];
                *(double2*)&xv[2] = *(const double2*)&Bx[c_l][ty][x_l + 2];
                *(double2*)&xv[4] = *(const double2*)&Bx[c_l][ty][x_l + 4];
#pragma unroll
                for (int tx = 0; tx < 3; ++tx) {
                    const double* wp = &Wl[c_l * 9 + ty * 3 + tx][oc_l];
                    double wr[4];
                    *(double2*)&wr[0] = *(const double2*)(wp + 0);
                    *(double2*)&wr[2] = *(const double2*)(wp + 2);
#pragma unroll
                    for (int i = 0; i < 4; ++i)
#pragma unroll
                        for (int j = 0; j < 4; ++j)
                            acc[i][j] = fma(wr[i], xv[j + tx], acc[i][j]);
                }
            }
        }
    }
#pragma unroll
    for (int i = 0; i < 4; ++i) {
        int oc = oc0 + oc_l + i;
        double b = (double)bconv[oc];
        double4 st;
        st.x = acc[i][0] + b; st.y = acc[i][1] + b;
        st.z = acc[i][2] + b; st.w = acc[i][3] + b;
        *(double4*)&convb[((size_t)imgL * COUT + oc) * NPOS + y * 64 + x_l] = st;
    }
}

// ---- heads: reg(36)+cls(18) fp64 GEMM + softmax + decode + clip
__global__ __launch_bounds__(256) void heads_kernel(const double* __restrict__ convb,
                                                    const float* __restrict__ Wh,
                                                    const float* __restrict__ breg,
                                                    const float* __restrict__ bcls,
                                                    const float* __restrict__ im_size,
                                                    float* __restrict__ out_scores,
                                                    float4* __restrict__ out_props,
                                                    double* __restrict__ dscores,
                                                    double4* __restrict__ dprops,
                                                    int img_base) {
    const int tid = threadIdx.x;
    const int y = blockIdx.x;
    const int imgL = blockIdx.y;
    const int img_g = img_base + imgL;

    __shared__ double cl[64][64];
    __shared__ float wl[64][64];

    const int o = tid & 63;
    const int g = tid >> 6;
    double acc[16];
#pragma unroll
    for (int j = 0; j < 16; ++j) acc[j] = 0.0;

    for (int k0 = 0; k0 < CIN; k0 += 64) {
        __syncthreads();
        for (int idx = tid; idx < 4096; idx += 256) {
            int kl = idx >> 6, p = idx & 63;
            cl[kl][p] = convb[((size_t)imgL * COUT + k0 + kl) * NPOS + y * 64 + p];
        }
        for (int idx = tid; idx < 4096; idx += 256) {
            wl[idx >> 6][idx & 63] = Wh[(k0 + (idx >> 6)) * 64 + (idx & 63)];
        }
        __syncthreads();
        const bool ru = (o >= 36);
        for (int kl = 0; kl < 64; ++kl) {
            double w = (double)wl[kl][o];
#pragma unroll
            for (int j = 0; j < 16; ++j) {
                double v = cl[kl][g * 16 + j];
                if (ru) v = fmax(v, 0.0);
                acc[j] = fma(w, v, acc[j]);
            }
        }
    }
    __syncthreads();
    double bias = (o < 36) ? (double)breg[o] : (o < 54 ? (double)bcls[o - 36] : 0.0);
#pragma unroll
    for (int j = 0; j < 16; ++j) cl[o][g * 16 + j] = acc[j] + bias;
    __syncthreads();

    const double im_h = (double)im_size[img_g * 2 + 0];
    const double im_w = (double)im_size[img_g * 2 + 1];
    const double xmax = im_w - 1.0, ymax = im_h - 1.0;

    for (int t = tid; t < 576; t += 256) {
        int p = t / 9;
        int a = t - p * 9;
        double dx = cl[a * 4 + 0][p], dy = cl[a * 4 + 1][p];
        double dw = cl[a * 4 + 2][p], dh = cl[a * 4 + 3][p];
        double c0 = cl[36 + a][p], c1 = cl[45 + a][p];
        double mm = fmax(c0, c1);
        double e0 = exp(c0 - mm), e1 = exp(c1 - mm);
        double sc = e0 / (e0 + e1);

        double sx = (double)p * 16.0, sy = (double)y * 16.0;
        double a0 = dANC[a][0] + sx, a1 = dANC[a][1] + sy;
        double a2 = dANC[a][2] + sx, a3 = dANC[a][3] + sy;
        double w_ = a2 - a0 + 1.0, h_ = a3 - a1 + 1.0;
        double cx = a0 + 0.5 * w_, cy = a1 + 0.5 * h_;
        double pcx = dx * cx, pcy = dy * cy;
        double pw = exp(dw) * w_, ph = exp(dh) * h_;
        double x1 = pcx - 0.5 * pw, y1 = pcy - 0.5 * ph;
        double x2 = pcx + 0.5 * pw, y2 = pcy + 0.5 * ph;
        x1 = fmin(fmax(x1, 0.0), xmax);
        y1 = fmin(fmax(y1, 0.0), ymax);
        x2 = fmin(fmax(x2, 0.0), xmax);
        y2 = fmin(fmax(y2, 0.0), ymax);

        int pp = y * 64 + p;
        size_t si = (size_t)img_g * NSC + (size_t)a * NPOS + pp;   // anchor-major
        size_t pi = (size_t)img_g * NSC + (size_t)pp * 9 + a;      // position-major
        out_scores[si] = (float)sc;
        dscores[si] = sc;
        double4 db; db.x = x1; db.y = y1; db.z = x2; db.w = y2;
        dprops[pi] = db;
        out_props[pi] = make_float4((float)x1, (float)y1, (float)x2, (float)y2);
    }
}

// ---- exact 3000th-largest score bit pattern (u64 radix select)
__global__ __launch_bounds__(256) void topk_select(const double* __restrict__ dscores,
                                                   u64* __restrict__ Tsel) {
    const int img = blockIdx.x;
    const int tid = threadIdx.x;
    const u64* sb = (const u64*)(dscores + (size_t)img * NSC);
    __shared__ uint32_t hist[256];
    __shared__ u64 s_prefix;
    __shared__ uint32_t s_rem;
    if (tid == 0) { s_prefix = 0ull; s_rem = PRE_TOPN; }
    for (int pass = 0; pass < 8; ++pass) {
        int shift = 56 - pass * 8;
        hist[tid] = 0;
        __syncthreads();
        u64 pmask = pass ? (~0ull << (shift + 8)) : 0ull;
        u64 pref = s_prefix;
        for (int i = tid; i < NSC; i += 256) {
            u64 v = sb[i];
            if ((v & pmask) == pref) atomicAdd(&hist[(uint32_t)(v >> shift) & 0xFFu], 1u);
        }
        __syncthreads();
        if (tid == 0) {
            uint32_t rem = s_rem, cum = 0;
            int b = 255;
            for (; b > 0; --b) {
                if (cum + hist[b] >= rem) break;
                cum += hist[b];
            }
            s_prefix = pref | ((u64)(uint32_t)b << shift);
            s_rem = rem - cum;
        }
        __syncthreads();
    }
    if (tid == 0) Tsel[img] = s_prefix;
}

// ---- compact >=T, exact bitonic sort desc by (score, -idx), gather
__global__ __launch_bounds__(1024) void sort_gather(const double* __restrict__ dscores,
                                                    const double4* __restrict__ dprops,
                                                    const u64* __restrict__ Tsel,
                                                    double4* __restrict__ dboxes) {
    const int img = blockIdx.x;
    const int tid = threadIdx.x;
    __shared__ u64 skey[4096];
    __shared__ unsigned short sidx[4096];
    __shared__ int cnt;
    if (tid == 0) cnt = 0;
    for (int i = tid; i < 4096; i += 1024) { skey[i] = 0ull; sidx[i] = 0xFFFF; }
    __syncthreads();
    const u64 T = Tsel[img];
    const u64* sb = (const u64*)(dscores + (size_t)img * NSC);
    for (int i = tid; i < NSC; i += 1024) {
        u64 v = sb[i];
        if (v >= T) {
            int p = atomicAdd(&cnt, 1);
            if (p < 4096) { skey[p] = v; sidx[p] = (unsigned short)i; }
        }
    }
    __syncthreads();
    for (int k = 2; k <= 4096; k <<= 1) {
        for (int j = k >> 1; j > 0; j >>= 1) {
            for (int i = tid; i < 4096; i += 1024) {
                int ixj = i ^ j;
                if (ixj > i) {
                    u64 ka = skey[i], kb = skey[ixj];
                    unsigned short ia = sidx[i], ib = sidx[ixj];
                    bool aw = (ka < kb) || (ka == kb && ia > ib);
                    bool up = (i & k) == 0;
                    if (up ? aw : !aw) {
                        skey[i] = kb; skey[ixj] = ka;
                        sidx[i] = ib; sidx[ixj] = ia;
                    }
                }
            }
            __syncthreads();
        }
    }
    for (int t = tid; t < PRE_TOPN; t += 1024) {
        unsigned int idx = sidx[t];
        dboxes[(size_t)img * PRE_TOPN + t] = dprops[(size_t)img * NSC + idx];
    }
}

// ---- suppression bitmask (fp64 IoU): mask[i] bit j = IoU>0.7 && j>i
__global__ __launch_bounds__(256) void iou_mask_kernel(const double4* __restrict__ dboxes,
                                                       u64* __restrict__ mask) {
    const int tid = threadIdx.x;
    const int ib = blockIdx.x;
    const int img = blockIdx.y;
    const int i = ib * 64 + (tid >> 2);
    if (i >= PRE_TOPN) return;
    const double4 bi = dboxes[(size_t)img * PRE_TOPN + i];
    const double ai = (bi.z - bi.x) * (bi.w - bi.y);
    for (int w = (tid & 3); w < NWORDS; w += 4) {
        const int jbase = w * 64;
        u64 m = 0;
        if (jbase + 63 > i) {
            const int jmax = min(64, PRE_TOPN - jbase);
            for (int b = 0; b < jmax; ++b) {
                int j = jbase + b;
                if (j > i) {
                    double4 bj = dboxes[(size_t)img * PRE_TOPN + j];
                    double aj = (bj.z - bj.x) * (bj.w - bj.y);
                    double ltx = fmax(bi.x, bj.x), lty = fmax(bi.y, bj.y);
                    double rbx = fmin(bi.z, bj.z), rby = fmin(bi.w, bj.w);
                    double iw = fmax(rbx - ltx, 0.0), ih = fmax(rby - lty, 0.0);
                    double inter = iw * ih;
                    double iou = inter / (ai + aj - inter + 1e-9);
                    if (iou > 0.7) m |= (1ull << b);
                }
            }
        }
        mask[((size_t)img * PRE_TOPN + i) * MSTRIDE + w] = m;
    }
}

// ---- greedy walk (1 wave / image) + emit 300 boxes (zero-padded)
__global__ __launch_bounds__(64) void nms_walk(const double4* __restrict__ dboxes,
                                               const u64* __restrict__ mask,
                                               float4* __restrict__ outb) {
    const int img = blockIdx.x;
    const int lane = threadIdx.x;
    __shared__ u64 removed[NWORDS];
    __shared__ short kept[POST_TOPN];
    __shared__ int nk;
    if (lane < NWORDS) removed[lane] = 0ull;
    if (lane == 0) nk = 0;
    __syncthreads();
    for (int i = 0; i < PRE_TOPN; ++i) {
        u64 rw = removed[i >> 6];
        int cur = nk;
        if (!((rw >> (i & 63)) & 1ull)) {
            if (lane == 0) { kept[cur] = (short)i; nk = cur + 1; }
            if (cur + 1 >= POST_TOPN) break;
            if (lane < NWORDS)
                removed[lane] |= mask[((size_t)img * PRE_TOPN + i) * MSTRIDE + lane];
        }
        __syncthreads();
    }
    __syncthreads();
    const int n = nk;
    for (int r = lane; r < POST_TOPN; r += 64) {
        float4 v = make_float4(0.f, 0.f, 0.f, 0.f);
        if (r < n) {
            double4 d = dboxes[(size_t)img * PRE_TOPN + kept[r]];
            v = make_float4((float)d.x, (float)d.y, (float)d.z, (float)d.w);
        }
        outb[img * POST_TOPN + r] = v;
    }
}

extern "C" void kernel_launch(void* const* d_in, const int* in_sizes, int n_in,
                              void* d_out, int out_size, void* d_ws, size_t ws_size,
                              hipStream_t stream) {
    const float* x = (const float*)d_in[0];
    const float* im_size = (const float*)d_in[1];
    const float* Wconv = (const float*)d_in[2];
    const float* bconv = (const float*)d_in[3];
    const float* Wreg = (const float*)d_in[4];
    const float* breg = (const float*)d_in[5];
    const float* Wcls = (const float*)d_in[6];
    const float* bcls = (const float*)d_in[7];

    float* outf = (float*)d_out;
    float4* out_boxes = (float4*)outf;                               // 8*300*4
    float* out_scores = outf + NIMG * POST_TOPN * 4;                 // 8*36864
    float4* out_props = (float4*)(out_scores + (size_t)NIMG * NSC);  // 8*36864*4

    char* ws = (char*)d_ws;
    const size_t WT_OFF = 0;                                         // Wtd2: 8*4608*66 f64
    const size_t WH_OFF = WT_OFF + (size_t)8 * 4608 * WROW * 8;
    const size_t TS_OFF = WH_OFF + (size_t)512 * 64 * 4;
    const size_t VAR_OFF = TS_OFF + 64;
    const size_t DS_OFF = (VAR_OFF + 4 + 255) & ~(size_t)255;
    const size_t DP_OFF = DS_OFF + (size_t)NIMG * NSC * 8;
    const size_t DB_OFF = DP_OFF + (size_t)NIMG * NSC * 32;
    const size_t MK_OFF = DB_OFF + (size_t)NIMG * PRE_TOPN * 32;
    const size_t CV_OFF = (MK_OFF + (size_t)NIMG * PRE_TOPN * MSTRIDE * 8 + 255) & ~(size_t)255;

    double* Wtd2 = (double*)(ws + WT_OFF);
    float* Wh = (float*)(ws + WH_OFF);
    u64* Tsel = (u64*)(ws + TS_OFF);
    int* variant = (int*)(ws + VAR_OFF);
    double* dscores = (double*)(ws + DS_OFF);
    double4* dprops = (double4*)(ws + DP_OFF);
    double4* dboxes = (double4*)(ws + DB_OFF);
    u64* mask = (u64*)(ws + MK_OFF);
    double* convb = (double*)(ws + CV_OFF);

    const size_t per_img = (size_t)COUT * NPOS * 8;
    int CH = 1;
    if (ws_size > CV_OFF + per_img) {
        size_t avail = (ws_size - CV_OFF) / per_img;
        CH = (int)(avail > 8 ? 8 : avail);
        if (CH < 1) CH = 1;
    }

    transpose_wconv_f64<<<dim3(144, 16), 256, 0, stream>>>(Wconv, Wtd2);
    build_wheads<<<128, 256, 0, stream>>>(Wreg, Wcls, Wh);
    mfma_probe<<<1, 64, 0, stream>>>(variant);

    for (int base = 0; base < NIMG; base += CH) {
        int n = NIMG - base;
        if (n > CH) n = CH;
        conv_mfma<<<dim3(8, 32, n), 512, 0, stream>>>(x, Wtd2, bconv, convb, variant, base);
        conv_valu<<<dim3(8, 64, n), 256, 0, stream>>>(x, Wtd2, bconv, convb, variant, base);
        heads_kernel<<<dim3(64, n), 256, 0, stream>>>(convb, Wh, breg, bcls, im_size,
                                                      out_scores, out_props,
                                                      dscores, dprops, base);
    }
    topk_select<<<NIMG, 256, 0, stream>>>(dscores, Tsel);
    sort_gather<<<NIMG, 1024, 0, stream>>>(dscores, dprops, Tsel, dboxes);
    iou_mask_kernel<<<dim3(NWORDS, NIMG), 256, 0, stream>>>(dboxes, mask);
    nms_walk<<<NIMG, 64, 0, stream>>>(dboxes, mask, out_boxes);
}

// Round 12
// 3689.222 us; speedup vs baseline: 1.0242x; 1.0242x over previous
//
#include <hip/hip_runtime.h>
#include <stdint.h>

typedef unsigned long long u64;
typedef double v4d __attribute__((ext_vector_type(4)));

#define NIMG 8
#define CIN 512
#define COUT 512
#define NPOS 4096            // 64*64
#define NSC 36864            // 9*64*64
#define PRE_TOPN 3000
#define POST_TOPN 300
#define NWORDS 47            // ceil(3000/64)
#define MSTRIDE 48           // padded words per mask row
#define WROWF 68             // padded W row (floats); 17 x 16B units
#define WCH_F 2448           // 36*68 floats per chunk
#define WBUF_B 9792          // 36*68*4 bytes per W buffer
#define XBUF 816             // 4ci * 3rows * 68 f32 per chunk

__constant__ double dANC[9][4] = {
    {-83.0, -39.0, 100.0, 56.0},   {-175.0, -87.0, 192.0, 104.0},
    {-359.0, -183.0, 376.0, 200.0},{-55.0, -55.0, 72.0, 72.0},
    {-119.0, -119.0, 136.0, 136.0},{-247.0, -247.0, 264.0, 264.0},
    {-35.0, -79.0, 52.0, 96.0},    {-79.0, -167.0, 96.0, 184.0},
    {-167.0, -343.0, 184.0, 360.0}};

static __device__ __forceinline__ void gload16(const void* g, void* l) {
    __builtin_amdgcn_global_load_lds(
        (const __attribute__((address_space(1))) void*)g,
        (__attribute__((address_space(3))) void*)l, 16, 0, 0);
}

// ---- W transpose: W_conv [512oc][4608k] -> Wtf [8 octile][4608k][68] f32 (64 + 4 pad)
__global__ __launch_bounds__(256) void transpose_wconv_f32(const float* __restrict__ W,
                                                           float* __restrict__ Wtf) {
    __shared__ float t[32][33];
    int k0 = blockIdx.x * 32;
    int o0 = blockIdx.y * 32;
    int tid = threadIdx.x;
    for (int idx = tid; idx < 1024; idx += 256) {
        int r = idx >> 5, c = idx & 31;
        t[r][c] = W[(size_t)(o0 + r) * 4608 + k0 + c];
    }
    __syncthreads();
    for (int idx = tid; idx < 1024; idx += 256) {
        int r = idx >> 5, c = idx & 31;
        int oc = o0 + c;
        Wtf[((size_t)(oc >> 6) * 4608 + (k0 + r)) * WROWF + (oc & 63)] = t[c][r];
    }
}

// ---- heads W: Wh [512k][64o]  (o<36: W_reg, 36..53: W_cls, rest 0)
__global__ __launch_bounds__(256) void build_wheads(const float* __restrict__ Wreg,
                                                    const float* __restrict__ Wcls,
                                                    float* __restrict__ Wh) {
    int g = blockIdx.x * 256 + threadIdx.x;
    if (g >= 512 * 64) return;
    int k = g >> 6, o = g & 63;
    float v = 0.f;
    if (o < 36) v = Wreg[o * 512 + k];
    else if (o < 54) v = Wcls[(o - 36) * 512 + k];
    Wh[g] = v;
}

// ---- MFMA layout probe: MFMA chain vs exact int reference (verified HW layout -> variant)
__global__ __launch_bounds__(64) void mfma_probe(int* __restrict__ variant) {
    __shared__ double AA[72][16];   // [K][m] : A[m][K] = m*73 + K + 1
    __shared__ double BB[72][16];   // [K][n] : B[K][n] = K*17 + 3n + 1
    const int L = threadIdx.x;
    for (int i = L; i < 72 * 16; i += 64) {
        int K = i >> 4, c = i & 15;
        AA[K][c] = (double)(c * 73 + K + 1);
        BB[K][c] = (double)(K * 17 + 3 * c + 1);
    }
    __syncthreads();
    const int lg = L >> 4, lm = L & 15;
    v4d accN = {0.0, 0.0, 0.0, 0.0};
    v4d accS = {0.0, 0.0, 0.0, 0.0};
#pragma unroll
    for (int k4 = 0; k4 < 18; ++k4) {
        double a = AA[4 * k4 + lg][lm];
        double b = BB[4 * k4 + lg][lm];
        accN = __builtin_amdgcn_mfma_f64_16x16x4f64(a, b, accN, 0, 0, 0);
        accS = __builtin_amdgcn_mfma_f64_16x16x4f64(b, a, accS, 0, 0, 0);
    }
    int found = 255;
    for (int v = 0; v < 8; ++v) {
        bool ok = true;
        for (int r = 0; r < 4; ++r) {
            int m, n;
            int dm = v & 3;
            if (dm == 0)      { m = 4 * lg + r; n = lm; }
            else if (dm == 1) { m = lm; n = 4 * lg + r; }
            else if (dm == 2) { m = lg + 4 * r; n = lm; }
            else              { m = lm; n = lg + 4 * r; }
            long long ref = 0;
            for (int K = 0; K < 72; ++K)
                ref += (long long)(m * 73 + K + 1) * (long long)(K * 17 + 3 * n + 1);
            double got = (v < 4) ? accN[r] : accS[r];
            ok = ok && (got == (double)ref);
        }
        if (__all(ok) && found == 255) found = v;
    }
    if (L == 0) *variant = found;
}

// ---- conv 3x3 SAME via f64 MFMA; 8 waves/block (16oc x 32pos per wave);
// W AND X in LDS as f32 (cvt at read, exact); W staged fully by global_load_lds.
// LDS = 2*(9792 + 3264) = 25.5 KB -> high residency.
__global__ __launch_bounds__(512) void conv_mfma(const float* __restrict__ X,
                                                 const float* __restrict__ Wtf,
                                                 const float* __restrict__ bconv,
                                                 double* __restrict__ convb,
                                                 const int* __restrict__ variant,
                                                 int img_base) {
    const int vr = *variant;
    if (vr > 7) return;
    const int tid = threadIdx.x;
    const int wv = tid >> 6;        // 0..7
    const int lane = tid & 63;
    const int lg = lane >> 4;
    const int lm = lane & 15;
    const int ocg = wv >> 1;        // oc group 0..3
    const int posb = (wv & 1) * 32; // pos half
    const int octile = blockIdx.x;
    const int oc0 = octile * 64;
    const int y = blockIdx.y;
    const int imgL = blockIdx.z;
    const int img_g = img_base + imgL;

    __shared__ float Wl[2][36][WROWF];  // A panel f32 (9792 B each)
    __shared__ float Xl[2][4][3][68];   // B panel f32 (3264 B each)
    char* wl0 = (char*)&Wl[0][0][0];
    float* xl0 = &Xl[0][0][0][0];

    v4d acc[2];
    acc[0] = (v4d){0.0, 0.0, 0.0, 0.0};
    acc[1] = (v4d){0.0, 0.0, 0.0, 0.0};

    // B row offsets for the 9 K4-steps of a 4-ci chunk (flat k = c*9 + ty*3 + tx)
    int boff[9];
#pragma unroll
    for (int k4 = 0; k4 < 9; ++k4) {
        int row = k4 * 4 + lg;
        int c = row / 9;
        int t = row - 9 * c;
        int ty = t / 3;
        int tx = t - 3 * ty;
        boff[k4] = (c * 3 + ty) * 68 + tx + posb + lm;
    }

    // X staging descriptors: 816 f32 per chunk, 2 slots/thread (512 threads)
    int xli1, xoff0, xoff1;
    {
        int idx = tid;   // always < 816
        int c_l = idx / 204;
        int rem = idx - c_l * 204;
        int r = rem / 68;
        int xx = rem - r * 68;
        int yy = y + r - 1;
        int xg = xx - 1;
        xoff0 = (xx < 66 && (unsigned)yy < 64u && (unsigned)xg < 64u)
                    ? ((img_g * CIN + c_l) * 64 + yy) * 64 + xg : -1;
    }
    {
        int idx = 512 + tid;
        xli1 = (idx < 816) ? idx : -1;
        xoff1 = -1;
        if (idx < 816) {
            int c_l = idx / 204;
            int rem = idx - c_l * 204;
            int r = rem / 68;
            int xx = rem - r * 68;
            int yy = y + r - 1;
            int xg = xx - 1;
            if (xx < 66 && (unsigned)yy < 64u && (unsigned)xg < 64u)
                xoff1 = ((img_g * CIN + c_l) * 64 + yy) * 64 + xg;
        }
    }
    // W DMA descriptors: 612 16B-units/chunk = 1 full 512-round + 100-unit masked round
    int woff0, woff1;
    {
        int u = tid;
        int row = u / 17, cp = u - 17 * row;
        woff0 = (octile * 4608 + row) * WROWF + cp * 4;
    }
    {
        int u = 512 + tid;
        int row = u / 17, cp = u - 17 * row;
        woff1 = (octile * 4608 + row) * WROWF + cp * 4;
    }

    float xr0, xr1;

#define WDMA(c, par) { \
    gload16(&Wtf[(size_t)woff0 + (size_t)(c) * WCH_F], \
            wl0 + (size_t)(par) * WBUF_B + (size_t)tid * 16); \
    if (tid < 100) \
        gload16(&Wtf[(size_t)woff1 + (size_t)(c) * WCH_F], \
                wl0 + (size_t)(par) * WBUF_B + (size_t)(512 + tid) * 16); }

#define LOADR(c) { \
    xr0 = (xoff0 >= 0) ? X[(size_t)xoff0 + (size_t)(c) * 16384] : 0.f; \
    xr1 = (xoff1 >= 0) ? X[(size_t)xoff1 + (size_t)(c) * 16384] : 0.f; }

#define WRITER(par) { \
    xl0[(size_t)(par) * XBUF + tid] = xr0; \
    if (xli1 >= 0) xl0[(size_t)(par) * XBUF + xli1] = xr1; }

    // prologue: stage chunk 0 into buffer 0
    WDMA(0, 0);
    LOADR(0);
    WRITER(0);
    __syncthreads();   // drains DMA (vmcnt 0) + makes writes visible

    const bool swapped = (vr >= 4);
    const int aoff = ocg * 16 + lm;

    for (int c = 0; c < 128; ++c) {
        const int par = c & 1;
        if (c < 127) { WDMA(c + 1, par ^ 1); LOADR(c + 1); }   // async, fly under MFMA
        const float* wb = &Wl[par][0][0];
        const float* bx = xl0 + (size_t)par * XBUF;
        if (!swapped) {
#pragma unroll
            for (int k4 = 0; k4 < 9; ++k4) {
                double a = (double)wb[(4 * k4 + lg) * WROWF + aoff];  // f32->f64 exact
                const float* bp = bx + boff[k4];
                double b0 = (double)bp[0];
                double b1 = (double)bp[16];
                acc[0] = __builtin_amdgcn_mfma_f64_16x16x4f64(a, b0, acc[0], 0, 0, 0);
                acc[1] = __builtin_amdgcn_mfma_f64_16x16x4f64(a, b1, acc[1], 0, 0, 0);
            }
        } else {
#pragma unroll
            for (int k4 = 0; k4 < 9; ++k4) {
                double a = (double)wb[(4 * k4 + lg) * WROWF + aoff];
                const float* bp = bx + boff[k4];
                double b0 = (double)bp[0];
                double b1 = (double)bp[16];
                acc[0] = __builtin_amdgcn_mfma_f64_16x16x4f64(b0, a, acc[0], 0, 0, 0);
                acc[1] = __builtin_amdgcn_mfma_f64_16x16x4f64(b1, a, acc[1], 0, 0, 0);
            }
        }
        if (c < 127) { WRITER(par ^ 1); }   // xr waits land here, post-compute
        __syncthreads();
    }
#undef WDMA
#undef LOADR
#undef WRITER

    // epilogue via verified variant decode
    const int dm = vr & 3;
#pragma unroll
    for (int q = 0; q < 2; ++q) {
#pragma unroll
        for (int r = 0; r < 4; ++r) {
            int m, n;
            if (dm == 0)      { m = 4 * lg + r; n = lm; }
            else if (dm == 1) { m = lm; n = 4 * lg + r; }
            else if (dm == 2) { m = lg + 4 * r; n = lm; }
            else              { m = lm; n = lg + 4 * r; }
            int oc = oc0 + ocg * 16 + m;
            int xp = posb + q * 16 + n;
            convb[((size_t)imgL * COUT + oc) * NPOS + y * 64 + xp] =
                acc[q][r] + (double)bconv[oc];
        }
    }
}

// ---- conv 3x3 SAME, fp64 VALU fallback (runs only if probe found no variant)
__global__ __launch_bounds__(256) void conv_valu(const float* __restrict__ X,
                                                 const float* __restrict__ Wtf,
                                                 const float* __restrict__ bconv,
                                                 double* __restrict__ convb,
                                                 const int* __restrict__ variant,
                                                 int img_base) {
    if (*variant <= 7) return;
    const int tid = threadIdx.x;
    const int octile = blockIdx.x;
    const int oc0 = octile * 64;
    const int y = blockIdx.y;
    const int imgL = blockIdx.z;
    const int img_g = img_base + imgL;
    const int x_l = (tid & 15) * 4;
    const int oc_l = (tid >> 4) * 4;

    __shared__ double Wl[72][64];
    __shared__ double Bx[8][3][68];

    double acc[4][4];
#pragma unroll
    for (int i = 0; i < 4; ++i)
#pragma unroll
        for (int j = 0; j < 4; ++j) acc[i][j] = 0.0;

    for (int cc = 0; cc < CIN; cc += 8) {
        __syncthreads();
        for (int idx = tid; idx < 8 * 3 * 68; idx += 256) {
            int c_l = idx / 204;
            int rem = idx - c_l * 204;
            int r = rem / 68;
            int xx = rem - r * 68;
            int yy = y + r - 1;
            int xg = xx - 1;
            float v = 0.f;
            if (xx < 66 && (unsigned)yy < 64u && (unsigned)xg < 64u)
                v = X[(((size_t)img_g * CIN + cc + c_l) * 64 + yy) * 64 + xg];
            Bx[c_l][r][xx] = (double)v;
        }
        for (int idx = tid; idx < 72 * 64; idx += 256) {
            int kl = idx >> 6, col = idx & 63;
            Wl[kl][col] = (double)Wtf[((size_t)octile * 4608 + cc * 9 + kl) * WROWF + col];
        }
        __syncthreads();
#pragma unroll 2
        for (int c_l = 0; c_l < 8; ++c_l) {
#pragma unroll
            for (int ty = 0; ty < 3; ++ty) {
                double xv[6];
                *(double2*)&xv[0] = *(const double2*)&Bx[c_l][ty][x_l + 0];
                *(double2*)&xv[2] = *(const double2*)&Bx[c_l][ty][x_l + 2];
                *(double2*)&xv[4] = *(const double2*)&Bx[c_l][ty][x_l + 4];
#pragma unroll
                for (int tx = 0; tx < 3; ++tx) {
                    const double* wp = &Wl[c_l * 9 + ty * 3 + tx][oc_l];
                    double wr[4];
                    *(double2*)&wr[0] = *(const double2*)(wp + 0);
                    *(double2*)&wr[2] = *(const double2*)(wp + 2);
#pragma unroll
                    for (int i = 0; i < 4; ++i)
#pragma unroll
                        for (int j = 0; j < 4; ++j)
                            acc[i][j] = fma(wr[i], xv[j + tx], acc[i][j]);
                }
            }
        }
    }
#pragma unroll
    for (int i = 0; i < 4; ++i) {
        int oc = oc0 + oc_l + i;
        double b = (double)bconv[oc];
        double4 st;
        st.x = acc[i][0] + b; st.y = acc[i][1] + b;
        st.z = acc[i][2] + b; st.w = acc[i][3] + b;
        *(double4*)&convb[((size_t)imgL * COUT + oc) * NPOS + y * 64 + x_l] = st;
    }
}

// ---- heads: reg(36)+cls(18) fp64 GEMM + softmax + decode + clip
__global__ __launch_bounds__(256) void heads_kernel(const double* __restrict__ convb,
                                                    const float* __restrict__ Wh,
                                                    const float* __restrict__ breg,
                                                    const float* __restrict__ bcls,
                                                    const float* __restrict__ im_size,
                                                    float* __restrict__ out_scores,
                                                    float4* __restrict__ out_props,
                                                    double* __restrict__ dscores,
                                                    double4* __restrict__ dprops,
                                                    int img_base) {
    const int tid = threadIdx.x;
    const int y = blockIdx.x;
    const int imgL = blockIdx.y;
    const int img_g = img_base + imgL;

    __shared__ double cl[64][64];
    __shared__ float wl[64][64];

    const int o = tid & 63;
    const int g = tid >> 6;
    double acc[16];
#pragma unroll
    for (int j = 0; j < 16; ++j) acc[j] = 0.0;

    for (int k0 = 0; k0 < CIN; k0 += 64) {
        __syncthreads();
        for (int idx = tid; idx < 4096; idx += 256) {
            int kl = idx >> 6, p = idx & 63;
            cl[kl][p] = convb[((size_t)imgL * COUT + k0 + kl) * NPOS + y * 64 + p];
        }
        for (int idx = tid; idx < 4096; idx += 256) {
            wl[idx >> 6][idx & 63] = Wh[(k0 + (idx >> 6)) * 64 + (idx & 63)];
        }
        __syncthreads();
        const bool ru = (o >= 36);
        for (int kl = 0; kl < 64; ++kl) {
            double w = (double)wl[kl][o];
#pragma unroll
            for (int j = 0; j < 16; ++j) {
                double v = cl[kl][g * 16 + j];
                if (ru) v = fmax(v, 0.0);
                acc[j] = fma(w, v, acc[j]);
            }
        }
    }
    __syncthreads();
    double bias = (o < 36) ? (double)breg[o] : (o < 54 ? (double)bcls[o - 36] : 0.0);
#pragma unroll
    for (int j = 0; j < 16; ++j) cl[o][g * 16 + j] = acc[j] + bias;
    __syncthreads();

    const double im_h = (double)im_size[img_g * 2 + 0];
    const double im_w = (double)im_size[img_g * 2 + 1];
    const double xmax = im_w - 1.0, ymax = im_h - 1.0;

    for (int t = tid; t < 576; t += 256) {
        int p = t / 9;
        int a = t - p * 9;
        double dx = cl[a * 4 + 0][p], dy = cl[a * 4 + 1][p];
        double dw = cl[a * 4 + 2][p], dh = cl[a * 4 + 3][p];
        double c0 = cl[36 + a][p], c1 = cl[45 + a][p];
        double mm = fmax(c0, c1);
        double e0 = exp(c0 - mm), e1 = exp(c1 - mm);
        double sc = e0 / (e0 + e1);

        double sx = (double)p * 16.0, sy = (double)y * 16.0;
        double a0 = dANC[a][0] + sx, a1 = dANC[a][1] + sy;
        double a2 = dANC[a][2] + sx, a3 = dANC[a][3] + sy;
        double w_ = a2 - a0 + 1.0, h_ = a3 - a1 + 1.0;
        double cx = a0 + 0.5 * w_, cy = a1 + 0.5 * h_;
        double pcx = dx * cx, pcy = dy * cy;
        double pw = exp(dw) * w_, ph = exp(dh) * h_;
        double x1 = pcx - 0.5 * pw, y1 = pcy - 0.5 * ph;
        double x2 = pcx + 0.5 * pw, y2 = pcy + 0.5 * ph;
        x1 = fmin(fmax(x1, 0.0), xmax);
        y1 = fmin(fmax(y1, 0.0), ymax);
        x2 = fmin(fmax(x2, 0.0), xmax);
        y2 = fmin(fmax(y2, 0.0), ymax);

        int pp = y * 64 + p;
        size_t si = (size_t)img_g * NSC + (size_t)a * NPOS + pp;   // anchor-major
        size_t pi = (size_t)img_g * NSC + (size_t)pp * 9 + a;      // position-major
        out_scores[si] = (float)sc;
        dscores[si] = sc;
        double4 db; db.x = x1; db.y = y1; db.z = x2; db.w = y2;
        dprops[pi] = db;
        out_props[pi] = make_float4((float)x1, (float)y1, (float)x2, (float)y2);
    }
}

// ---- exact 3000th-largest score bit pattern (u64 radix select)
__global__ __launch_bounds__(256) void topk_select(const double* __restrict__ dscores,
                                                   u64* __restrict__ Tsel) {
    const int img = blockIdx.x;
    const int tid = threadIdx.x;
    const u64* sb = (const u64*)(dscores + (size_t)img * NSC);
    __shared__ uint32_t hist[256];
    __shared__ u64 s_prefix;
    __shared__ uint32_t s_rem;
    if (tid == 0) { s_prefix = 0ull; s_rem = PRE_TOPN; }
    for (int pass = 0; pass < 8; ++pass) {
        int shift = 56 - pass * 8;
        hist[tid] = 0;
        __syncthreads();
        u64 pmask = pass ? (~0ull << (shift + 8)) : 0ull;
        u64 pref = s_prefix;
        for (int i = tid; i < NSC; i += 256) {
            u64 v = sb[i];
            if ((v & pmask) == pref) atomicAdd(&hist[(uint32_t)(v >> shift) & 0xFFu], 1u);
        }
        __syncthreads();
        if (tid == 0) {
            uint32_t rem = s_rem, cum = 0;
            int b = 255;
            for (; b > 0; --b) {
                if (cum + hist[b] >= rem) break;
                cum += hist[b];
            }
            s_prefix = pref | ((u64)(uint32_t)b << shift);
            s_rem = rem - cum;
        }
        __syncthreads();
    }
    if (tid == 0) Tsel[img] = s_prefix;
}

// ---- compact >=T, exact bitonic sort desc by (score, -idx), gather
__global__ __launch_bounds__(1024) void sort_gather(const double* __restrict__ dscores,
                                                    const double4* __restrict__ dprops,
                                                    const u64* __restrict__ Tsel,
                                                    double4* __restrict__ dboxes) {
    const int img = blockIdx.x;
    const int tid = threadIdx.x;
    __shared__ u64 skey[4096];
    __shared__ unsigned short sidx[4096];
    __shared__ int cnt;
    if (tid == 0) cnt = 0;
    for (int i = tid; i < 4096; i += 1024) { skey[i] = 0ull; sidx[i] = 0xFFFF; }
    __syncthreads();
    const u64 T = Tsel[img];
    const u64* sb = (const u64*)(dscores + (size_t)img * NSC);
    for (int i = tid; i < NSC; i += 1024) {
        u64 v = sb[i];
        if (v >= T) {
            int p = atomicAdd(&cnt, 1);
            if (p < 4096) { skey[p] = v; sidx[p] = (unsigned short)i; }
        }
    }
    __syncthreads();
    for (int k = 2; k <= 4096; k <<= 1) {
        for (int j = k >> 1; j > 0; j >>= 1) {
            for (int i = tid; i < 4096; i += 1024) {
                int ixj = i ^ j;
                if (ixj > i) {
                    u64 ka = skey[i], kb = skey[ixj];
                    unsigned short ia = sidx[i], ib = sidx[ixj];
                    bool aw = (ka < kb) || (ka == kb && ia > ib);
                    bool up = (i & k) == 0;
                    if (up ? aw : !aw) {
                        skey[i] = kb; skey[ixj] = ka;
                        sidx[i] = ib; sidx[ixj] = ia;
                    }
                }
            }
            __syncthreads();
        }
    }
    for (int t = tid; t < PRE_TOPN; t += 1024) {
        unsigned int idx = sidx[t];
        dboxes[(size_t)img * PRE_TOPN + t] = dprops[(size_t)img * NSC + idx];
    }
}

// ---- suppression bitmask (fp64 IoU): mask[i] bit j = IoU>0.7 && j>i
__global__ __launch_bounds__(256) void iou_mask_kernel(const double4* __restrict__ dboxes,
                                                       u64* __restrict__ mask) {
    const int tid = threadIdx.x;
    const int ib = blockIdx.x;
    const int img = blockIdx.y;
    const int i = ib * 64 + (tid >> 2);
    if (i >= PRE_TOPN) return;
    const double4 bi = dboxes[(size_t)img * PRE_TOPN + i];
    const double ai = (bi.z - bi.x) * (bi.w - bi.y);
    for (int w = (tid & 3); w < NWORDS; w += 4) {
        const int jbase = w * 64;
        u64 m = 0;
        if (jbase + 63 > i) {
            const int jmax = min(64, PRE_TOPN - jbase);
            for (int b = 0; b < jmax; ++b) {
                int j = jbase + b;
                if (j > i) {
                    double4 bj = dboxes[(size_t)img * PRE_TOPN + j];
                    double aj = (bj.z - bj.x) * (bj.w - bj.y);
                    double ltx = fmax(bi.x, bj.x), lty = fmax(bi.y, bj.y);
                    double rbx = fmin(bi.z, bj.z), rby = fmin(bi.w, bj.w);
                    double iw = fmax(rbx - ltx, 0.0), ih = fmax(rby - lty, 0.0);
                    double inter = iw * ih;
                    double iou = inter / (ai + aj - inter + 1e-9);
                    if (iou > 0.7) m |= (1ull << b);
                }
            }
        }
        mask[((size_t)img * PRE_TOPN + i) * MSTRIDE + w] = m;
    }
}

// ---- greedy walk (1 wave / image) + emit 300 boxes (zero-padded)
__global__ __launch_bounds__(64) void nms_walk(const double4* __restrict__ dboxes,
                                               const u64* __restrict__ mask,
                                               float4* __restrict__ outb) {
    const int img = blockIdx.x;
    const int lane = threadIdx.x;
    __shared__ u64 removed[NWORDS];
    __shared__ short kept[POST_TOPN];
    __shared__ int nk;
    if (lane < NWORDS) removed[lane] = 0ull;
    if (lane == 0) nk = 0;
    __syncthreads();
    for (int i = 0; i < PRE_TOPN; ++i) {
        u64 rw = removed[i >> 6];
        int cur = nk;
        if (!((rw >> (i & 63)) & 1ull)) {
            if (lane == 0) { kept[cur] = (short)i; nk = cur + 1; }
            if (cur + 1 >= POST_TOPN) break;
            if (lane < NWORDS)
                removed[lane] |= mask[((size_t)img * PRE_TOPN + i) * MSTRIDE + lane];
        }
        __syncthreads();
    }
    __syncthreads();
    const int n = nk;
    for (int r = lane; r < POST_TOPN; r += 64) {
        float4 v = make_float4(0.f, 0.f, 0.f, 0.f);
        if (r < n) {
            double4 d = dboxes[(size_t)img * PRE_TOPN + kept[r]];
            v = make_float4((float)d.x, (float)d.y, (float)d.z, (float)d.w);
        }
        outb[img * POST_TOPN + r] = v;
    }
}

extern "C" void kernel_launch(void* const* d_in, const int* in_sizes, int n_in,
                              void* d_out, int out_size, void* d_ws, size_t ws_size,
                              hipStream_t stream) {
    const float* x = (const float*)d_in[0];
    const float* im_size = (const float*)d_in[1];
    const float* Wconv = (const float*)d_in[2];
    const float* bconv = (const float*)d_in[3];
    const float* Wreg = (const float*)d_in[4];
    const float* breg = (const float*)d_in[5];
    const float* Wcls = (const float*)d_in[6];
    const float* bcls = (const float*)d_in[7];

    float* outf = (float*)d_out;
    float4* out_boxes = (float4*)outf;                               // 8*300*4
    float* out_scores = outf + NIMG * POST_TOPN * 4;                 // 8*36864
    float4* out_props = (float4*)(out_scores + (size_t)NIMG * NSC);  // 8*36864*4

    char* ws = (char*)d_ws;
    const size_t WT_OFF = 0;                                         // Wtf: 8*4608*68 f32
    const size_t WH_OFF = WT_OFF + (size_t)8 * 4608 * WROWF * 4;
    const size_t TS_OFF = WH_OFF + (size_t)512 * 64 * 4;
    const size_t VAR_OFF = TS_OFF + 64;
    const size_t DS_OFF = (VAR_OFF + 4 + 255) & ~(size_t)255;
    const size_t DP_OFF = DS_OFF + (size_t)NIMG * NSC * 8;
    const size_t DB_OFF = DP_OFF + (size_t)NIMG * NSC * 32;
    const size_t MK_OFF = DB_OFF + (size_t)NIMG * PRE_TOPN * 32;
    const size_t CV_OFF = (MK_OFF + (size_t)NIMG * PRE_TOPN * MSTRIDE * 8 + 255) & ~(size_t)255;

    float* Wtf = (float*)(ws + WT_OFF);
    float* Wh = (float*)(ws + WH_OFF);
    u64* Tsel = (u64*)(ws + TS_OFF);
    int* variant = (int*)(ws + VAR_OFF);
    double* dscores = (double*)(ws + DS_OFF);
    double4* dprops = (double4*)(ws + DP_OFF);
    double4* dboxes = (double4*)(ws + DB_OFF);
    u64* mask = (u64*)(ws + MK_OFF);
    double* convb = (double*)(ws + CV_OFF);

    const size_t per_img = (size_t)COUT * NPOS * 8;
    int CH = 1;
    if (ws_size > CV_OFF + per_img) {
        size_t avail = (ws_size - CV_OFF) / per_img;
        CH = (int)(avail > 8 ? 8 : avail);
        if (CH < 1) CH = 1;
    }

    transpose_wconv_f32<<<dim3(144, 16), 256, 0, stream>>>(Wconv, Wtf);
    build_wheads<<<128, 256, 0, stream>>>(Wreg, Wcls, Wh);
    mfma_probe<<<1, 64, 0, stream>>>(variant);

    for (int base = 0; base < NIMG; base += CH) {
        int n = NIMG - base;
        if (n > CH) n = CH;
        conv_mfma<<<dim3(8, 64, n), 512, 0, stream>>>(x, Wtf, bconv, convb, variant, base);
        conv_valu<<<dim3(8, 64, n), 256, 0, stream>>>(x, Wtf, bconv, convb, variant, base);
        heads_kernel<<<dim3(64, n), 256, 0, stream>>>(convb, Wh, breg, bcls, im_size,
                                                      out_scores, out_props,
                                                      dscores, dprops, base);
    }
    topk_select<<<NIMG, 256, 0, stream>>>(dscores, Tsel);
    sort_gather<<<NIMG, 1024, 0, stream>>>(dscores, dprops, Tsel, dboxes);
    iou_mask_kernel<<<dim3(NWORDS, NIMG), 256, 0, stream>>>(dboxes, mask);
    nms_walk<<<NIMG, 64, 0, stream>>>(dboxes, mask, out_boxes);
}

// Round 13
// 3600.613 us; speedup vs baseline: 1.0494x; 1.0246x over previous
//
#include <hip/hip_runtime.h>
#include <stdint.h>

typedef unsigned long long u64;
typedef double v4d __attribute__((ext_vector_type(4)));

#define NIMG 8
#define CIN 512
#define COUT 512
#define NPOS 4096            // 64*64
#define NSC 36864            // 9*64*64
#define PRE_TOPN 3000
#define POST_TOPN 300
#define NWORDS 47            // ceil(3000/64)
#define MSTRIDE 48           // padded words per mask row
#define WROWF 80             // padded W row (floats); stride 80 -> 2-way banks max
#define WCH_F 5760           // 72*80 floats per 8-ci chunk
#define WBUF_B 23040         // 72*80*4 bytes per W buffer
#define WUNITS 1440          // 72*20 16B units per chunk
#define XBUF 1920            // 8ci * 3rows * 80 floats per chunk
#define XVALID 1632          // 8ci * 3rows * 68 staged elements

__constant__ double dANC[9][4] = {
    {-83.0, -39.0, 100.0, 56.0},   {-175.0, -87.0, 192.0, 104.0},
    {-359.0, -183.0, 376.0, 200.0},{-55.0, -55.0, 72.0, 72.0},
    {-119.0, -119.0, 136.0, 136.0},{-247.0, -247.0, 264.0, 264.0},
    {-35.0, -79.0, 52.0, 96.0},    {-79.0, -167.0, 96.0, 184.0},
    {-167.0, -343.0, 184.0, 360.0}};

static __device__ __forceinline__ void gload16(const void* g, void* l) {
    __builtin_amdgcn_global_load_lds(
        (const __attribute__((address_space(1))) void*)g,
        (__attribute__((address_space(3))) void*)l, 16, 0, 0);
}

// ---- W transpose: W_conv [512oc][4608k] -> Wtf [8 octile][4608k][80] f32 (64 + 16 pad)
__global__ __launch_bounds__(256) void transpose_wconv_f32(const float* __restrict__ W,
                                                           float* __restrict__ Wtf) {
    __shared__ float t[32][33];
    int k0 = blockIdx.x * 32;
    int o0 = blockIdx.y * 32;
    int tid = threadIdx.x;
    for (int idx = tid; idx < 1024; idx += 256) {
        int r = idx >> 5, c = idx & 31;
        t[r][c] = W[(size_t)(o0 + r) * 4608 + k0 + c];
    }
    __syncthreads();
    for (int idx = tid; idx < 1024; idx += 256) {
        int r = idx >> 5, c = idx & 31;
        int oc = o0 + c;
        Wtf[((size_t)(oc >> 6) * 4608 + (k0 + r)) * WROWF + (oc & 63)] = t[c][r];
    }
}

// ---- heads W: Wh [512k][64o]  (o<36: W_reg, 36..53: W_cls, rest 0)
__global__ __launch_bounds__(256) void build_wheads(const float* __restrict__ Wreg,
                                                    const float* __restrict__ Wcls,
                                                    float* __restrict__ Wh) {
    int g = blockIdx.x * 256 + threadIdx.x;
    if (g >= 512 * 64) return;
    int k = g >> 6, o = g & 63;
    float v = 0.f;
    if (o < 36) v = Wreg[o * 512 + k];
    else if (o < 54) v = Wcls[(o - 36) * 512 + k];
    Wh[g] = v;
}

// ---- MFMA layout probe: MFMA chain vs exact int reference (verified HW layout -> variant)
__global__ __launch_bounds__(64) void mfma_probe(int* __restrict__ variant) {
    __shared__ double AA[72][16];   // [K][m] : A[m][K] = m*73 + K + 1
    __shared__ double BB[72][16];   // [K][n] : B[K][n] = K*17 + 3n + 1
    const int L = threadIdx.x;
    for (int i = L; i < 72 * 16; i += 64) {
        int K = i >> 4, c = i & 15;
        AA[K][c] = (double)(c * 73 + K + 1);
        BB[K][c] = (double)(K * 17 + 3 * c + 1);
    }
    __syncthreads();
    const int lg = L >> 4, lm = L & 15;
    v4d accN = {0.0, 0.0, 0.0, 0.0};
    v4d accS = {0.0, 0.0, 0.0, 0.0};
#pragma unroll
    for (int k4 = 0; k4 < 18; ++k4) {
        double a = AA[4 * k4 + lg][lm];
        double b = BB[4 * k4 + lg][lm];
        accN = __builtin_amdgcn_mfma_f64_16x16x4f64(a, b, accN, 0, 0, 0);
        accS = __builtin_amdgcn_mfma_f64_16x16x4f64(b, a, accS, 0, 0, 0);
    }
    int found = 255;
    for (int v = 0; v < 8; ++v) {
        bool ok = true;
        for (int r = 0; r < 4; ++r) {
            int m, n;
            int dm = v & 3;
            if (dm == 0)      { m = 4 * lg + r; n = lm; }
            else if (dm == 1) { m = lm; n = 4 * lg + r; }
            else if (dm == 2) { m = lg + 4 * r; n = lm; }
            else              { m = lm; n = lg + 4 * r; }
            long long ref = 0;
            for (int K = 0; K < 72; ++K)
                ref += (long long)(m * 73 + K + 1) * (long long)(K * 17 + 3 * n + 1);
            double got = (v < 4) ? accN[r] : accS[r];
            ok = ok && (got == (double)ref);
        }
        if (__all(ok) && found == 255) found = v;
    }
    if (L == 0) *variant = found;
}

// ---- conv 3x3 SAME via f64 MFMA; 8 waves/block (16oc x 32pos per wave);
// 8-ci chunks (72 K-rows, 64 barriers); LDS strides 80 (2-way banks max);
// W staged via global_load_lds dbuf; X f32 LDS, cvt at read (exact).
__global__ __launch_bounds__(512) void conv_mfma(const float* __restrict__ X,
                                                 const float* __restrict__ Wtf,
                                                 const float* __restrict__ bconv,
                                                 double* __restrict__ convb,
                                                 const int* __restrict__ variant,
                                                 int img_base) {
    const int vr = *variant;
    if (vr > 7) return;
    const int tid = threadIdx.x;
    const int wv = tid >> 6;        // 0..7
    const int lane = tid & 63;
    const int lg = lane >> 4;
    const int lm = lane & 15;
    const int ocg = wv >> 1;        // oc group 0..3
    const int posb = (wv & 1) * 32; // pos half
    const int octile = blockIdx.x;
    const int oc0 = octile * 64;
    const int y = blockIdx.y;
    const int imgL = blockIdx.z;
    const int img_g = img_base + imgL;

    __shared__ float Wl[2][72][WROWF];  // A panel f32 (23040 B each)
    __shared__ float Xl[2][8][3][80];   // B panel f32 (7680 B each)
    char* wl0 = (char*)&Wl[0][0][0];
    float* xl0 = &Xl[0][0][0][0];

    v4d acc[2];
    acc[0] = (v4d){0.0, 0.0, 0.0, 0.0};
    acc[1] = (v4d){0.0, 0.0, 0.0, 0.0};

    // B row offsets for the 18 K4-steps of an 8-ci chunk (flat k = c*9 + ty*3 + tx)
    int boff[18];
#pragma unroll
    for (int k4 = 0; k4 < 18; ++k4) {
        int row = k4 * 4 + lg;
        int c = row / 9;
        int t = row - 9 * c;
        int ty = t / 3;
        int tx = t - 3 * ty;
        boff[k4] = c * 240 + ty * 80 + tx + posb + lm;
    }

    // X staging: 1632 valid f32/chunk, 4 slots/thread (last masked tid<96)
    int xli[4], xoff[4];
#pragma unroll
    for (int i = 0; i < 4; ++i) {
        int idx = tid + i * 512;
        xli[i] = -1;
        xoff[i] = -1;
        if (idx < XVALID) {
            int c_l = idx / 204;
            int rem = idx - c_l * 204;
            int r = rem / 68;
            int xx = rem - r * 68;
            xli[i] = c_l * 240 + r * 80 + xx;
            int yy = y + r - 1;
            int xg = xx - 1;
            if (xx < 66 && (unsigned)yy < 64u && (unsigned)xg < 64u)
                xoff[i] = ((img_g * CIN + c_l) * 64 + yy) * 64 + xg;
        }
    }
    // W DMA descriptors: 1440 16B-units/chunk = 2 full 512 rounds + 416-unit masked
    int woff[3];
#pragma unroll
    for (int i = 0; i < 3; ++i) {
        int u = i * 512 + tid;
        int row = u / 20, cp = u - 20 * row;
        woff[i] = (octile * 4608 + row) * WROWF + cp * 4;
    }

    float xr[4];

#define WDMA(c, par) { \
    gload16(&Wtf[(size_t)woff[0] + (size_t)(c) * WCH_F], \
            wl0 + (size_t)(par) * WBUF_B + (size_t)tid * 16); \
    gload16(&Wtf[(size_t)woff[1] + (size_t)(c) * WCH_F], \
            wl0 + (size_t)(par) * WBUF_B + (size_t)(512 + tid) * 16); \
    if (tid < 416) \
        gload16(&Wtf[(size_t)woff[2] + (size_t)(c) * WCH_F], \
                wl0 + (size_t)(par) * WBUF_B + (size_t)(1024 + tid) * 16); }

#define LOADR(c) { \
    _Pragma("unroll") \
    for (int i = 0; i < 4; ++i) \
        xr[i] = (xoff[i] >= 0) ? X[(size_t)xoff[i] + (size_t)(c) * 32768] : 0.f; }

#define WRITER(par) { \
    _Pragma("unroll") \
    for (int i = 0; i < 4; ++i) \
        if (xli[i] >= 0) xl0[(size_t)(par) * XBUF + xli[i]] = xr[i]; }

    // prologue: stage chunk 0 into buffer 0
    WDMA(0, 0);
    LOADR(0);
    WRITER(0);
    __syncthreads();   // drains DMA (vmcnt 0) + makes writes visible

    const bool swapped = (vr >= 4);
    const int aoff = ocg * 16 + lm;

    for (int c = 0; c < 64; ++c) {
        const int par = c & 1;
        if (c < 63) { WDMA(c + 1, par ^ 1); LOADR(c + 1); }   // async, fly under MFMA
        const float* wb = &Wl[par][0][0];
        const float* bx = xl0 + (size_t)par * XBUF;
        if (!swapped) {
#pragma unroll
            for (int k4 = 0; k4 < 18; ++k4) {
                double a = (double)wb[(4 * k4 + lg) * WROWF + aoff];  // f32->f64 exact
                const float* bp = bx + boff[k4];
                double b0 = (double)bp[0];
                double b1 = (double)bp[16];
                acc[0] = __builtin_amdgcn_mfma_f64_16x16x4f64(a, b0, acc[0], 0, 0, 0);
                acc[1] = __builtin_amdgcn_mfma_f64_16x16x4f64(a, b1, acc[1], 0, 0, 0);
            }
        } else {
#pragma unroll
            for (int k4 = 0; k4 < 18; ++k4) {
                double a = (double)wb[(4 * k4 + lg) * WROWF + aoff];
                const float* bp = bx + boff[k4];
                double b0 = (double)bp[0];
                double b1 = (double)bp[16];
                acc[0] = __builtin_amdgcn_mfma_f64_16x16x4f64(b0, a, acc[0], 0, 0, 0);
                acc[1] = __builtin_amdgcn_mfma_f64_16x16x4f64(b1, a, acc[1], 0, 0, 0);
            }
        }
        if (c < 63) { WRITER(par ^ 1); }   // xr waits land here, post-compute
        __syncthreads();
    }
#undef WDMA
#undef LOADR
#undef WRITER

    // epilogue via verified variant decode
    const int dm = vr & 3;
#pragma unroll
    for (int q = 0; q < 2; ++q) {
#pragma unroll
        for (int r = 0; r < 4; ++r) {
            int m, n;
            if (dm == 0)      { m = 4 * lg + r; n = lm; }
            else if (dm == 1) { m = lm; n = 4 * lg + r; }
            else if (dm == 2) { m = lg + 4 * r; n = lm; }
            else              { m = lm; n = lg + 4 * r; }
            int oc = oc0 + ocg * 16 + m;
            int xp = posb + q * 16 + n;
            convb[((size_t)imgL * COUT + oc) * NPOS + y * 64 + xp] =
                acc[q][r] + (double)bconv[oc];
        }
    }
}

// ---- conv 3x3 SAME, fp64 VALU fallback (runs only if probe found no variant)
__global__ __launch_bounds__(256) void conv_valu(const float* __restrict__ X,
                                                 const float* __restrict__ Wtf,
                                                 const float* __restrict__ bconv,
                                                 double* __restrict__ convb,
                                                 const int* __restrict__ variant,
                                                 int img_base) {
    if (*variant <= 7) return;
    const int tid = threadIdx.x;
    const int octile = blockIdx.x;
    const int oc0 = octile * 64;
    const int y = blockIdx.y;
    const int imgL = blockIdx.z;
    const int img_g = img_base + imgL;
    const int x_l = (tid & 15) * 4;
    const int oc_l = (tid >> 4) * 4;

    __shared__ double Wl[72][64];
    __shared__ double Bx[8][3][68];

    double acc[4][4];
#pragma unroll
    for (int i = 0; i < 4; ++i)
#pragma unroll
        for (int j = 0; j < 4; ++j) acc[i][j] = 0.0;

    for (int cc = 0; cc < CIN; cc += 8) {
        __syncthreads();
        for (int idx = tid; idx < 8 * 3 * 68; idx += 256) {
            int c_l = idx / 204;
            int rem = idx - c_l * 204;
            int r = rem / 68;
            int xx = rem - r * 68;
            int yy = y + r - 1;
            int xg = xx - 1;
            float v = 0.f;
            if (xx < 66 && (unsigned)yy < 64u && (unsigned)xg < 64u)
                v = X[(((size_t)img_g * CIN + cc + c_l) * 64 + yy) * 64 + xg];
            Bx[c_l][r][xx] = (double)v;
        }
        for (int idx = tid; idx < 72 * 64; idx += 256) {
            int kl = idx >> 6, col = idx & 63;
            Wl[kl][col] = (double)Wtf[((size_t)octile * 4608 + cc * 9 + kl) * WROWF + col];
        }
        __syncthreads();
#pragma unroll 2
        for (int c_l = 0; c_l < 8; ++c_l) {
#pragma unroll
            for (int ty = 0; ty < 3; ++ty) {
                double xv[6];
                *(double2*)&xv[0] = *(const double2*)&Bx[c_l][ty][x_l + 0];
                *(double2*)&xv[2] = *(const double2*)&Bx[c_l][ty][x_l + 2];
                *(double2*)&xv[4] = *(const double2*)&Bx[c_l][ty][x_l + 4];
#pragma unroll
                for (int tx = 0; tx < 3; ++tx) {
                    const double* wp = &Wl[c_l * 9 + ty * 3 + tx][oc_l];
                    double wr[4];
                    *(double2*)&wr[0] = *(const double2*)(wp + 0);
                    *(double2*)&wr[2] = *(const double2*)(wp + 2);
#pragma unroll
                    for (int i = 0; i < 4; ++i)
#pragma unroll
                        for (int j = 0; j < 4; ++j)
                            acc[i][j] = fma(wr[i], xv[j + tx], acc[i][j]);
                }
            }
        }
    }
#pragma unroll
    for (int i = 0; i < 4; ++i) {
        int oc = oc0 + oc_l + i;
        double b = (double)bconv[oc];
        double4 st;
        st.x = acc[i][0] + b; st.y = acc[i][1] + b;
        st.z = acc[i][2] + b; st.w = acc[i][3] + b;
        *(double4*)&convb[((size_t)imgL * COUT + oc) * NPOS + y * 64 + x_l] = st;
    }
}

// ---- heads: reg(36)+cls(18) fp64 GEMM + softmax + decode + clip
__global__ __launch_bounds__(256) void heads_kernel(const double* __restrict__ convb,
                                                    const float* __restrict__ Wh,
                                                    const float* __restrict__ breg,
                                                    const float* __restrict__ bcls,
                                                    const float* __restrict__ im_size,
                                                    float* __restrict__ out_scores,
                                                    float4* __restrict__ out_props,
                                                    double* __restrict__ dscores,
                                                    double4* __restrict__ dprops,
                                                    int img_base) {
    const int tid = threadIdx.x;
    const int y = blockIdx.x;
    const int imgL = blockIdx.y;
    const int img_g = img_base + imgL;

    __shared__ double cl[64][64];
    __shared__ float wl[64][64];

    const int o = tid & 63;
    const int g = tid >> 6;
    double acc[16];
#pragma unroll
    for (int j = 0; j < 16; ++j) acc[j] = 0.0;

    for (int k0 = 0; k0 < CIN; k0 += 64) {
        __syncthreads();
        for (int idx = tid; idx < 4096; idx += 256) {
            int kl = idx >> 6, p = idx & 63;
            cl[kl][p] = convb[((size_t)imgL * COUT + k0 + kl) * NPOS + y * 64 + p];
        }
        for (int idx = tid; idx < 4096; idx += 256) {
            wl[idx >> 6][idx & 63] = Wh[(k0 + (idx >> 6)) * 64 + (idx & 63)];
        }
        __syncthreads();
        const bool ru = (o >= 36);
        for (int kl = 0; kl < 64; ++kl) {
            double w = (double)wl[kl][o];
#pragma unroll
            for (int j = 0; j < 16; ++j) {
                double v = cl[kl][g * 16 + j];
                if (ru) v = fmax(v, 0.0);
                acc[j] = fma(w, v, acc[j]);
            }
        }
    }
    __syncthreads();
    double bias = (o < 36) ? (double)breg[o] : (o < 54 ? (double)bcls[o - 36] : 0.0);
#pragma unroll
    for (int j = 0; j < 16; ++j) cl[o][g * 16 + j] = acc[j] + bias;
    __syncthreads();

    const double im_h = (double)im_size[img_g * 2 + 0];
    const double im_w = (double)im_size[img_g * 2 + 1];
    const double xmax = im_w - 1.0, ymax = im_h - 1.0;

    for (int t = tid; t < 576; t += 256) {
        int p = t / 9;
        int a = t - p * 9;
        double dx = cl[a * 4 + 0][p], dy = cl[a * 4 + 1][p];
        double dw = cl[a * 4 + 2][p], dh = cl[a * 4 + 3][p];
        double c0 = cl[36 + a][p], c1 = cl[45 + a][p];
        double mm = fmax(c0, c1);
        double e0 = exp(c0 - mm), e1 = exp(c1 - mm);
        double sc = e0 / (e0 + e1);

        double sx = (double)p * 16.0, sy = (double)y * 16.0;
        double a0 = dANC[a][0] + sx, a1 = dANC[a][1] + sy;
        double a2 = dANC[a][2] + sx, a3 = dANC[a][3] + sy;
        double w_ = a2 - a0 + 1.0, h_ = a3 - a1 + 1.0;
        double cx = a0 + 0.5 * w_, cy = a1 + 0.5 * h_;
        double pcx = dx * cx, pcy = dy * cy;
        double pw = exp(dw) * w_, ph = exp(dh) * h_;
        double x1 = pcx - 0.5 * pw, y1 = pcy - 0.5 * ph;
        double x2 = pcx + 0.5 * pw, y2 = pcy + 0.5 * ph;
        x1 = fmin(fmax(x1, 0.0), xmax);
        y1 = fmin(fmax(y1, 0.0), ymax);
        x2 = fmin(fmax(x2, 0.0), xmax);
        y2 = fmin(fmax(y2, 0.0), ymax);

        int pp = y * 64 + p;
        size_t si = (size_t)img_g * NSC + (size_t)a * NPOS + pp;   // anchor-major
        size_t pi = (size_t)img_g * NSC + (size_t)pp * 9 + a;      // position-major
        out_scores[si] = (float)sc;
        dscores[si] = sc;
        double4 db; db.x = x1; db.y = y1; db.z = x2; db.w = y2;
        dprops[pi] = db;
        out_props[pi] = make_float4((float)x1, (float)y1, (float)x2, (float)y2);
    }
}

// ---- exact 3000th-largest score bit pattern (u64 radix select)
__global__ __launch_bounds__(256) void topk_select(const double* __restrict__ dscores,
                                                   u64* __restrict__ Tsel) {
    const int img = blockIdx.x;
    const int tid = threadIdx.x;
    const u64* sb = (const u64*)(dscores + (size_t)img * NSC);
    __shared__ uint32_t hist[256];
    __shared__ u64 s_prefix;
    __shared__ uint32_t s_rem;
    if (tid == 0) { s_prefix = 0ull; s_rem = PRE_TOPN; }
    for (int pass = 0; pass < 8; ++pass) {
        int shift = 56 - pass * 8;
        hist[tid] = 0;
        __syncthreads();
        u64 pmask = pass ? (~0ull << (shift + 8)) : 0ull;
        u64 pref = s_prefix;
        for (int i = tid; i < NSC; i += 256) {
            u64 v = sb[i];
            if ((v & pmask) == pref) atomicAdd(&hist[(uint32_t)(v >> shift) & 0xFFu], 1u);
        }
        __syncthreads();
        if (tid == 0) {
            uint32_t rem = s_rem, cum = 0;
            int b = 255;
            for (; b > 0; --b) {
                if (cum + hist[b] >= rem) break;
                cum += hist[b];
            }
            s_prefix = pref | ((u64)(uint32_t)b << shift);
            s_rem = rem - cum;
        }
        __syncthreads();
    }
    if (tid == 0) Tsel[img] = s_prefix;
}

// ---- compact >=T, exact bitonic sort desc by (score, -idx), gather
__global__ __launch_bounds__(1024) void sort_gather(const double* __restrict__ dscores,
                                                    const double4* __restrict__ dprops,
                                                    const u64* __restrict__ Tsel,
                                                    double4* __restrict__ dboxes) {
    const int img = blockIdx.x;
    const int tid = threadIdx.x;
    __shared__ u64 skey[4096];
    __shared__ unsigned short sidx[4096];
    __shared__ int cnt;
    if (tid == 0) cnt = 0;
    for (int i = tid; i < 4096; i += 1024) { skey[i] = 0ull; sidx[i] = 0xFFFF; }
    __syncthreads();
    const u64 T = Tsel[img];
    const u64* sb = (const u64*)(dscores + (size_t)img * NSC);
    for (int i = tid; i < NSC; i += 1024) {
        u64 v = sb[i];
        if (v >= T) {
            int p = atomicAdd(&cnt, 1);
            if (p < 4096) { skey[p] = v; sidx[p] = (unsigned short)i; }
        }
    }
    __syncthreads();
    for (int k = 2; k <= 4096; k <<= 1) {
        for (int j = k >> 1; j > 0; j >>= 1) {
            for (int i = tid; i < 4096; i += 1024) {
                int ixj = i ^ j;
                if (ixj > i) {
                    u64 ka = skey[i], kb = skey[ixj];
                    unsigned short ia = sidx[i], ib = sidx[ixj];
                    bool aw = (ka < kb) || (ka == kb && ia > ib);
                    bool up = (i & k) == 0;
                    if (up ? aw : !aw) {
                        skey[i] = kb; skey[ixj] = ka;
                        sidx[i] = ib; sidx[ixj] = ia;
                    }
                }
            }
            __syncthreads();
        }
    }
    for (int t = tid; t < PRE_TOPN; t += 1024) {
        unsigned int idx = sidx[t];
        dboxes[(size_t)img * PRE_TOPN + t] = dprops[(size_t)img * NSC + idx];
    }
}

// ---- suppression bitmask (fp64 IoU): mask[i] bit j = IoU>0.7 && j>i
__global__ __launch_bounds__(256) void iou_mask_kernel(const double4* __restrict__ dboxes,
                                                       u64* __restrict__ mask) {
    const int tid = threadIdx.x;
    const int ib = blockIdx.x;
    const int img = blockIdx.y;
    const int i = ib * 64 + (tid >> 2);
    if (i >= PRE_TOPN) return;
    const double4 bi = dboxes[(size_t)img * PRE_TOPN + i];
    const double ai = (bi.z - bi.x) * (bi.w - bi.y);
    for (int w = (tid & 3); w < NWORDS; w += 4) {
        const int jbase = w * 64;
        u64 m = 0;
        if (jbase + 63 > i) {
            const int jmax = min(64, PRE_TOPN - jbase);
            for (int b = 0; b < jmax; ++b) {
                int j = jbase + b;
                if (j > i) {
                    double4 bj = dboxes[(size_t)img * PRE_TOPN + j];
                    double aj = (bj.z - bj.x) * (bj.w - bj.y);
                    double ltx = fmax(bi.x, bj.x), lty = fmax(bi.y, bj.y);
                    double rbx = fmin(bi.z, bj.z), rby = fmin(bi.w, bj.w);
                    double iw = fmax(rbx - ltx, 0.0), ih = fmax(rby - lty, 0.0);
                    double inter = iw * ih;
                    double iou = inter / (ai + aj - inter + 1e-9);
                    if (iou > 0.7) m |= (1ull << b);
                }
            }
        }
        mask[((size_t)img * PRE_TOPN + i) * MSTRIDE + w] = m;
    }
}

// ---- greedy walk (1 wave / image) + emit 300 boxes (zero-padded)
__global__ __launch_bounds__(64) void nms_walk(const double4* __restrict__ dboxes,
                                               const u64* __restrict__ mask,
                                               float4* __restrict__ outb) {
    const int img = blockIdx.x;
    const int lane = threadIdx.x;
    __shared__ u64 removed[NWORDS];
    __shared__ short kept[POST_TOPN];
    __shared__ int nk;
    if (lane < NWORDS) removed[lane] = 0ull;
    if (lane == 0) nk = 0;
    __syncthreads();
    for (int i = 0; i < PRE_TOPN; ++i) {
        u64 rw = removed[i >> 6];
        int cur = nk;
        if (!((rw >> (i & 63)) & 1ull)) {
            if (lane == 0) { kept[cur] = (short)i; nk = cur + 1; }
            if (cur + 1 >= POST_TOPN) break;
            if (lane < NWORDS)
                removed[lane] |= mask[((size_t)img * PRE_TOPN + i) * MSTRIDE + lane];
        }
        __syncthreads();
    }
    __syncthreads();
    const int n = nk;
    for (int r = lane; r < POST_TOPN; r += 64) {
        float4 v = make_float4(0.f, 0.f, 0.f, 0.f);
        if (r < n) {
            double4 d = dboxes[(size_t)img * PRE_TOPN + kept[r]];
            v = make_float4((float)d.x, (float)d.y, (float)d.z, (float)d.w);
        }
        outb[img * POST_TOPN + r] = v;
    }
}

extern "C" void kernel_launch(void* const* d_in, const int* in_sizes, int n_in,
                              void* d_out, int out_size, void* d_ws, size_t ws_size,
                              hipStream_t stream) {
    const float* x = (const float*)d_in[0];
    const float* im_size = (const float*)d_in[1];
    const float* Wconv = (const float*)d_in[2];
    const float* bconv = (const float*)d_in[3];
    const float* Wreg = (const float*)d_in[4];
    const float* breg = (const float*)d_in[5];
    const float* Wcls = (const float*)d_in[6];
    const float* bcls = (const float*)d_in[7];

    float* outf = (float*)d_out;
    float4* out_boxes = (float4*)outf;                               // 8*300*4
    float* out_scores = outf + NIMG * POST_TOPN * 4;                 // 8*36864
    float4* out_props = (float4*)(out_scores + (size_t)NIMG * NSC);  // 8*36864*4

    char* ws = (char*)d_ws;
    const size_t WT_OFF = 0;                                         // Wtf: 8*4608*80 f32
    const size_t WH_OFF = WT_OFF + (size_t)8 * 4608 * WROWF * 4;
    const size_t TS_OFF = WH_OFF + (size_t)512 * 64 * 4;
    const size_t VAR_OFF = TS_OFF + 64;
    const size_t DS_OFF = (VAR_OFF + 4 + 255) & ~(size_t)255;
    const size_t DP_OFF = DS_OFF + (size_t)NIMG * NSC * 8;
    const size_t DB_OFF = DP_OFF + (size_t)NIMG * NSC * 32;
    const size_t MK_OFF = DB_OFF + (size_t)NIMG * PRE_TOPN * 32;
    const size_t CV_OFF = (MK_OFF + (size_t)NIMG * PRE_TOPN * MSTRIDE * 8 + 255) & ~(size_t)255;

    float* Wtf = (float*)(ws + WT_OFF);
    float* Wh = (float*)(ws + WH_OFF);
    u64* Tsel = (u64*)(ws + TS_OFF);
    int* variant = (int*)(ws + VAR_OFF);
    double* dscores = (double*)(ws + DS_OFF);
    double4* dprops = (double4*)(ws + DP_OFF);
    double4* dboxes = (double4*)(ws + DB_OFF);
    u64* mask = (u64*)(ws + MK_OFF);
    double* convb = (double*)(ws + CV_OFF);

    const size_t per_img = (size_t)COUT * NPOS * 8;
    int CH = 1;
    if (ws_size > CV_OFF + per_img) {
        size_t avail = (ws_size - CV_OFF) / per_img;
        CH = (int)(avail > 8 ? 8 : avail);
        if (CH < 1) CH = 1;
    }

    transpose_wconv_f32<<<dim3(144, 16), 256, 0, stream>>>(Wconv, Wtf);
    build_wheads<<<128, 256, 0, stream>>>(Wreg, Wcls, Wh);
    mfma_probe<<<1, 64, 0, stream>>>(variant);

    for (int base = 0; base < NIMG; base += CH) {
        int n = NIMG - base;
        if (n > CH) n = CH;
        conv_mfma<<<dim3(8, 64, n), 512, 0, stream>>>(x, Wtf, bconv, convb, variant, base);
        conv_valu<<<dim3(8, 64, n), 256, 0, stream>>>(x, Wtf, bconv, convb, variant, base);
        heads_kernel<<<dim3(64, n), 256, 0, stream>>>(convb, Wh, breg, bcls, im_size,
                                                      out_scores, out_props,
                                                      dscores, dprops, base);
    }
    topk_select<<<NIMG, 256, 0, stream>>>(dscores, Tsel);
    sort_gather<<<NIMG, 1024, 0, stream>>>(dscores, dprops, Tsel, dboxes);
    iou_mask_kernel<<<dim3(NWORDS, NIMG), 256, 0, stream>>>(dboxes, mask);
    nms_walk<<<NIMG, 64, 0, stream>>>(dboxes, mask, out_boxes);
}

// Round 14
// 3551.318 us; speedup vs baseline: 1.0639x; 1.0139x over previous
//
#include <hip/hip_runtime.h>
#include <stdint.h>

typedef unsigned long long u64;
typedef double v4d __attribute__((ext_vector_type(4)));

#define NIMG 8
#define CIN 512
#define COUT 512
#define NPOS 4096            // 64*64
#define NSC 36864            // 9*64*64
#define PRE_TOPN 3000
#define POST_TOPN 300
#define NWORDS 47            // ceil(3000/64)
#define MSTRIDE 48           // padded words per mask row
#define WROWF 80             // padded W row (floats); stride 80 -> 2-way banks max
#define WCH_F 5760           // 72*80 floats per 8-ci chunk
#define WBUF_B 23040         // 72*80*4 bytes per W buffer
#define XBUF 1920            // 8ci * 3rows * 80 floats per chunk
#define XVALID 1632          // 8ci * 3rows * 68 staged elements

__constant__ double dANC[9][4] = {
    {-83.0, -39.0, 100.0, 56.0},   {-175.0, -87.0, 192.0, 104.0},
    {-359.0, -183.0, 376.0, 200.0},{-55.0, -55.0, 72.0, 72.0},
    {-119.0, -119.0, 136.0, 136.0},{-247.0, -247.0, 264.0, 264.0},
    {-35.0, -79.0, 52.0, 96.0},    {-79.0, -167.0, 96.0, 184.0},
    {-167.0, -343.0, 184.0, 360.0}};

static __device__ __forceinline__ void gload16(const void* g, void* l) {
    __builtin_amdgcn_global_load_lds(
        (const __attribute__((address_space(1))) void*)g,
        (__attribute__((address_space(3))) void*)l, 16, 0, 0);
}

// ---- W transpose: W_conv [512oc][4608k] -> Wtf [8 octile][4608k][80] f32 (64 + 16 pad)
__global__ __launch_bounds__(256) void transpose_wconv_f32(const float* __restrict__ W,
                                                           float* __restrict__ Wtf) {
    __shared__ float t[32][33];
    int k0 = blockIdx.x * 32;
    int o0 = blockIdx.y * 32;
    int tid = threadIdx.x;
    for (int idx = tid; idx < 1024; idx += 256) {
        int r = idx >> 5, c = idx & 31;
        t[r][c] = W[(size_t)(o0 + r) * 4608 + k0 + c];
    }
    __syncthreads();
    for (int idx = tid; idx < 1024; idx += 256) {
        int r = idx >> 5, c = idx & 31;
        int oc = o0 + c;
        Wtf[((size_t)(oc >> 6) * 4608 + (k0 + r)) * WROWF + (oc & 63)] = t[c][r];
    }
}

// ---- heads W: Wh [512k][64o]  (o<36: W_reg, 36..53: W_cls, rest 0)
__global__ __launch_bounds__(256) void build_wheads(const float* __restrict__ Wreg,
                                                    const float* __restrict__ Wcls,
                                                    float* __restrict__ Wh) {
    int g = blockIdx.x * 256 + threadIdx.x;
    if (g >= 512 * 64) return;
    int k = g >> 6, o = g & 63;
    float v = 0.f;
    if (o < 36) v = Wreg[o * 512 + k];
    else if (o < 54) v = Wcls[(o - 36) * 512 + k];
    Wh[g] = v;
}

// ---- MFMA layout probe: MFMA chain vs exact int reference (verified HW layout -> variant)
__global__ __launch_bounds__(64) void mfma_probe(int* __restrict__ variant) {
    __shared__ double AA[72][16];   // [K][m] : A[m][K] = m*73 + K + 1
    __shared__ double BB[72][16];   // [K][n] : B[K][n] = K*17 + 3n + 1
    const int L = threadIdx.x;
    for (int i = L; i < 72 * 16; i += 64) {
        int K = i >> 4, c = i & 15;
        AA[K][c] = (double)(c * 73 + K + 1);
        BB[K][c] = (double)(K * 17 + 3 * c + 1);
    }
    __syncthreads();
    const int lg = L >> 4, lm = L & 15;
    v4d accN = {0.0, 0.0, 0.0, 0.0};
    v4d accS = {0.0, 0.0, 0.0, 0.0};
#pragma unroll
    for (int k4 = 0; k4 < 18; ++k4) {
        double a = AA[4 * k4 + lg][lm];
        double b = BB[4 * k4 + lg][lm];
        accN = __builtin_amdgcn_mfma_f64_16x16x4f64(a, b, accN, 0, 0, 0);
        accS = __builtin_amdgcn_mfma_f64_16x16x4f64(b, a, accS, 0, 0, 0);
    }
    int found = 255;
    for (int v = 0; v < 8; ++v) {
        bool ok = true;
        for (int r = 0; r < 4; ++r) {
            int m, n;
            int dm = v & 3;
            if (dm == 0)      { m = 4 * lg + r; n = lm; }
            else if (dm == 1) { m = lm; n = 4 * lg + r; }
            else if (dm == 2) { m = lg + 4 * r; n = lm; }
            else              { m = lm; n = lg + 4 * r; }
            long long ref = 0;
            for (int K = 0; K < 72; ++K)
                ref += (long long)(m * 73 + K + 1) * (long long)(K * 17 + 3 * n + 1);
            double got = (v < 4) ? accN[r] : accS[r];
            ok = ok && (got == (double)ref);
        }
        if (__all(ok) && found == 255) found = v;
    }
    if (L == 0) *variant = found;
}

// ---- conv 3x3 SAME via f64 MFMA; 8 waves/block (16oc x 32pos per wave);
// 8-ci chunks (72 K-rows, 64 barriers); LDS strides 80 (2-way banks max);
// W staged via global_load_lds dbuf; X f32 LDS, cvt at read (exact).
__global__ __launch_bounds__(512) void conv_mfma(const float* __restrict__ X,
                                                 const float* __restrict__ Wtf,
                                                 const float* __restrict__ bconv,
                                                 double* __restrict__ convb,
                                                 const int* __restrict__ variant,
                                                 int img_base) {
    const int vr = *variant;
    if (vr > 7) return;
    const int tid = threadIdx.x;
    const int wv = tid >> 6;        // 0..7
    const int lane = tid & 63;
    const int lg = lane >> 4;
    const int lm = lane & 15;
    const int ocg = wv >> 1;        // oc group 0..3
    const int posb = (wv & 1) * 32; // pos half
    const int octile = blockIdx.x;
    const int oc0 = octile * 64;
    const int y = blockIdx.y;
    const int imgL = blockIdx.z;
    const int img_g = img_base + imgL;

    __shared__ float Wl[2][72][WROWF];  // A panel f32 (23040 B each)
    __shared__ float Xl[2][8][3][80];   // B panel f32 (7680 B each)
    char* wl0 = (char*)&Wl[0][0][0];
    float* xl0 = &Xl[0][0][0][0];

    v4d acc[2];
    acc[0] = (v4d){0.0, 0.0, 0.0, 0.0};
    acc[1] = (v4d){0.0, 0.0, 0.0, 0.0};

    // B row offsets for the 18 K4-steps of an 8-ci chunk (flat k = c*9 + ty*3 + tx)
    int boff[18];
#pragma unroll
    for (int k4 = 0; k4 < 18; ++k4) {
        int row = k4 * 4 + lg;
        int c = row / 9;
        int t = row - 9 * c;
        int ty = t / 3;
        int tx = t - 3 * ty;
        boff[k4] = c * 240 + ty * 80 + tx + posb + lm;
    }

    // X staging: 1632 valid f32/chunk, 4 slots/thread (last masked tid<96)
    int xli[4], xoff[4];
#pragma unroll
    for (int i = 0; i < 4; ++i) {
        int idx = tid + i * 512;
        xli[i] = -1;
        xoff[i] = -1;
        if (idx < XVALID) {
            int c_l = idx / 204;
            int rem = idx - c_l * 204;
            int r = rem / 68;
            int xx = rem - r * 68;
            xli[i] = c_l * 240 + r * 80 + xx;
            int yy = y + r - 1;
            int xg = xx - 1;
            if (xx < 66 && (unsigned)yy < 64u && (unsigned)xg < 64u)
                xoff[i] = ((img_g * CIN + c_l) * 64 + yy) * 64 + xg;
        }
    }
    // W DMA descriptors: 1440 16B-units/chunk = 2 full 512 rounds + 416-unit masked
    int woff[3];
#pragma unroll
    for (int i = 0; i < 3; ++i) {
        int u = i * 512 + tid;
        int row = u / 20, cp = u - 20 * row;
        woff[i] = (octile * 4608 + row) * WROWF + cp * 4;
    }

    float xr[4];

#define WDMA(c, par) { \
    gload16(&Wtf[(size_t)woff[0] + (size_t)(c) * WCH_F], \
            wl0 + (size_t)(par) * WBUF_B + (size_t)tid * 16); \
    gload16(&Wtf[(size_t)woff[1] + (size_t)(c) * WCH_F], \
            wl0 + (size_t)(par) * WBUF_B + (size_t)(512 + tid) * 16); \
    if (tid < 416) \
        gload16(&Wtf[(size_t)woff[2] + (size_t)(c) * WCH_F], \
                wl0 + (size_t)(par) * WBUF_B + (size_t)(1024 + tid) * 16); }

#define LOADR(c) { \
    _Pragma("unroll") \
    for (int i = 0; i < 4; ++i) \
        xr[i] = (xoff[i] >= 0) ? X[(size_t)xoff[i] + (size_t)(c) * 32768] : 0.f; }

#define WRITER(par) { \
    _Pragma("unroll") \
    for (int i = 0; i < 4; ++i) \
        if (xli[i] >= 0) xl0[(size_t)(par) * XBUF + xli[i]] = xr[i]; }

    // prologue: stage chunk 0 into buffer 0
    WDMA(0, 0);
    LOADR(0);
    WRITER(0);
    __syncthreads();   // drains DMA (vmcnt 0) + makes writes visible

    const bool swapped = (vr >= 4);
    const int aoff = ocg * 16 + lm;

    for (int c = 0; c < 64; ++c) {
        const int par = c & 1;
        if (c < 63) { WDMA(c + 1, par ^ 1); LOADR(c + 1); }   // async, fly under MFMA
        const float* wb = &Wl[par][0][0];
        const float* bx = xl0 + (size_t)par * XBUF;
        if (!swapped) {
#pragma unroll
            for (int k4 = 0; k4 < 18; ++k4) {
                double a = (double)wb[(4 * k4 + lg) * WROWF + aoff];  // f32->f64 exact
                const float* bp = bx + boff[k4];
                double b0 = (double)bp[0];
                double b1 = (double)bp[16];
                acc[0] = __builtin_amdgcn_mfma_f64_16x16x4f64(a, b0, acc[0], 0, 0, 0);
                acc[1] = __builtin_amdgcn_mfma_f64_16x16x4f64(a, b1, acc[1], 0, 0, 0);
            }
        } else {
#pragma unroll
            for (int k4 = 0; k4 < 18; ++k4) {
                double a = (double)wb[(4 * k4 + lg) * WROWF + aoff];
                const float* bp = bx + boff[k4];
                double b0 = (double)bp[0];
                double b1 = (double)bp[16];
                acc[0] = __builtin_amdgcn_mfma_f64_16x16x4f64(b0, a, acc[0], 0, 0, 0);
                acc[1] = __builtin_amdgcn_mfma_f64_16x16x4f64(b1, a, acc[1], 0, 0, 0);
            }
        }
        if (c < 63) { WRITER(par ^ 1); }   // xr waits land here, post-compute
        __syncthreads();
    }
#undef WDMA
#undef LOADR
#undef WRITER

    // epilogue via verified variant decode
    const int dm = vr & 3;
#pragma unroll
    for (int q = 0; q < 2; ++q) {
#pragma unroll
        for (int r = 0; r < 4; ++r) {
            int m, n;
            if (dm == 0)      { m = 4 * lg + r; n = lm; }
            else if (dm == 1) { m = lm; n = 4 * lg + r; }
            else if (dm == 2) { m = lg + 4 * r; n = lm; }
            else              { m = lm; n = lg + 4 * r; }
            int oc = oc0 + ocg * 16 + m;
            int xp = posb + q * 16 + n;
            convb[((size_t)imgL * COUT + oc) * NPOS + y * 64 + xp] =
                acc[q][r] + (double)bconv[oc];
        }
    }
}

// ---- conv 3x3 SAME, fp64 VALU fallback (runs only if probe found no variant)
__global__ __launch_bounds__(256) void conv_valu(const float* __restrict__ X,
                                                 const float* __restrict__ Wtf,
                                                 const float* __restrict__ bconv,
                                                 double* __restrict__ convb,
                                                 const int* __restrict__ variant,
                                                 int img_base) {
    if (*variant <= 7) return;
    const int tid = threadIdx.x;
    const int octile = blockIdx.x;
    const int oc0 = octile * 64;
    const int y = blockIdx.y;
    const int imgL = blockIdx.z;
    const int img_g = img_base + imgL;
    const int x_l = (tid & 15) * 4;
    const int oc_l = (tid >> 4) * 4;

    __shared__ double Wl[72][64];
    __shared__ double Bx[8][3][68];

    double acc[4][4];
#pragma unroll
    for (int i = 0; i < 4; ++i)
#pragma unroll
        for (int j = 0; j < 4; ++j) acc[i][j] = 0.0;

    for (int cc = 0; cc < CIN; cc += 8) {
        __syncthreads();
        for (int idx = tid; idx < 8 * 3 * 68; idx += 256) {
            int c_l = idx / 204;
            int rem = idx - c_l * 204;
            int r = rem / 68;
            int xx = rem - r * 68;
            int yy = y + r - 1;
            int xg = xx - 1;
            float v = 0.f;
            if (xx < 66 && (unsigned)yy < 64u && (unsigned)xg < 64u)
                v = X[(((size_t)img_g * CIN + cc + c_l) * 64 + yy) * 64 + xg];
            Bx[c_l][r][xx] = (double)v;
        }
        for (int idx = tid; idx < 72 * 64; idx += 256) {
            int kl = idx >> 6, col = idx & 63;
            Wl[kl][col] = (double)Wtf[((size_t)octile * 4608 + cc * 9 + kl) * WROWF + col];
        }
        __syncthreads();
#pragma unroll 2
        for (int c_l = 0; c_l < 8; ++c_l) {
#pragma unroll
            for (int ty = 0; ty < 3; ++ty) {
                double xv[6];
                *(double2*)&xv[0] = *(const double2*)&Bx[c_l][ty][x_l + 0];
                *(double2*)&xv[2] = *(const double2*)&Bx[c_l][ty][x_l + 2];
                *(double2*)&xv[4] = *(const double2*)&Bx[c_l][ty][x_l + 4];
#pragma unroll
                for (int tx = 0; tx < 3; ++tx) {
                    const double* wp = &Wl[c_l * 9 + ty * 3 + tx][oc_l];
                    double wr[4];
                    *(double2*)&wr[0] = *(const double2*)(wp + 0);
                    *(double2*)&wr[2] = *(const double2*)(wp + 2);
#pragma unroll
                    for (int i = 0; i < 4; ++i)
#pragma unroll
                        for (int j = 0; j < 4; ++j)
                            acc[i][j] = fma(wr[i], xv[j + tx], acc[i][j]);
                }
            }
        }
    }
#pragma unroll
    for (int i = 0; i < 4; ++i) {
        int oc = oc0 + oc_l + i;
        double b = (double)bconv[oc];
        double4 st;
        st.x = acc[i][0] + b; st.y = acc[i][1] + b;
        st.z = acc[i][2] + b; st.w = acc[i][3] + b;
        *(double4*)&convb[((size_t)imgL * COUT + oc) * NPOS + y * 64 + x_l] = st;
    }
}

// ---- heads: reg(36)+cls(18) fp64 GEMM + softmax + decode + clip
__global__ __launch_bounds__(256) void heads_kernel(const double* __restrict__ convb,
                                                    const float* __restrict__ Wh,
                                                    const float* __restrict__ breg,
                                                    const float* __restrict__ bcls,
                                                    const float* __restrict__ im_size,
                                                    float* __restrict__ out_scores,
                                                    float4* __restrict__ out_props,
                                                    double* __restrict__ dscores,
                                                    double4* __restrict__ dprops,
                                                    int img_base) {
    const int tid = threadIdx.x;
    const int y = blockIdx.x;
    const int imgL = blockIdx.y;
    const int img_g = img_base + imgL;

    __shared__ double cl[64][64];
    __shared__ float wl[64][64];

    const int o = tid & 63;
    const int g = tid >> 6;
    double acc[16];
#pragma unroll
    for (int j = 0; j < 16; ++j) acc[j] = 0.0;

    for (int k0 = 0; k0 < CIN; k0 += 64) {
        __syncthreads();
        for (int idx = tid; idx < 4096; idx += 256) {
            int kl = idx >> 6, p = idx & 63;
            cl[kl][p] = convb[((size_t)imgL * COUT + k0 + kl) * NPOS + y * 64 + p];
        }
        for (int idx = tid; idx < 4096; idx += 256) {
            wl[idx >> 6][idx & 63] = Wh[(k0 + (idx >> 6)) * 64 + (idx & 63)];
        }
        __syncthreads();
        const bool ru = (o >= 36);
        for (int kl = 0; kl < 64; ++kl) {
            double w = (double)wl[kl][o];
#pragma unroll
            for (int j = 0; j < 16; ++j) {
                double v = cl[kl][g * 16 + j];
                if (ru) v = fmax(v, 0.0);
                acc[j] = fma(w, v, acc[j]);
            }
        }
    }
    __syncthreads();
    double bias = (o < 36) ? (double)breg[o] : (o < 54 ? (double)bcls[o - 36] : 0.0);
#pragma unroll
    for (int j = 0; j < 16; ++j) cl[o][g * 16 + j] = acc[j] + bias;
    __syncthreads();

    const double im_h = (double)im_size[img_g * 2 + 0];
    const double im_w = (double)im_size[img_g * 2 + 1];
    const double xmax = im_w - 1.0, ymax = im_h - 1.0;

    for (int t = tid; t < 576; t += 256) {
        int p = t / 9;
        int a = t - p * 9;
        double dx = cl[a * 4 + 0][p], dy = cl[a * 4 + 1][p];
        double dw = cl[a * 4 + 2][p], dh = cl[a * 4 + 3][p];
        double c0 = cl[36 + a][p], c1 = cl[45 + a][p];
        double mm = fmax(c0, c1);
        double e0 = exp(c0 - mm), e1 = exp(c1 - mm);
        double sc = e0 / (e0 + e1);

        double sx = (double)p * 16.0, sy = (double)y * 16.0;
        double a0 = dANC[a][0] + sx, a1 = dANC[a][1] + sy;
        double a2 = dANC[a][2] + sx, a3 = dANC[a][3] + sy;
        double w_ = a2 - a0 + 1.0, h_ = a3 - a1 + 1.0;
        double cx = a0 + 0.5 * w_, cy = a1 + 0.5 * h_;
        double pcx = dx * cx, pcy = dy * cy;
        double pw = exp(dw) * w_, ph = exp(dh) * h_;
        double x1 = pcx - 0.5 * pw, y1 = pcy - 0.5 * ph;
        double x2 = pcx + 0.5 * pw, y2 = pcy + 0.5 * ph;
        x1 = fmin(fmax(x1, 0.0), xmax);
        y1 = fmin(fmax(y1, 0.0), ymax);
        x2 = fmin(fmax(x2, 0.0), xmax);
        y2 = fmin(fmax(y2, 0.0), ymax);

        int pp = y * 64 + p;
        size_t si = (size_t)img_g * NSC + (size_t)a * NPOS + pp;   // anchor-major
        size_t pi = (size_t)img_g * NSC + (size_t)pp * 9 + a;      // position-major
        out_scores[si] = (float)sc;
        dscores[si] = sc;
        double4 db; db.x = x1; db.y = y1; db.z = x2; db.w = y2;
        dprops[pi] = db;
        out_props[pi] = make_float4((float)x1, (float)y1, (float)x2, (float)y2);
    }
}

// ---- exact 3000th-largest score bit pattern (u64 radix select)
__global__ __launch_bounds__(256) void topk_select(const double* __restrict__ dscores,
                                                   u64* __restrict__ Tsel) {
    const int img = blockIdx.x;
    const int tid = threadIdx.x;
    const u64* sb = (const u64*)(dscores + (size_t)img * NSC);
    __shared__ uint32_t hist[256];
    __shared__ u64 s_prefix;
    __shared__ uint32_t s_rem;
    if (tid == 0) { s_prefix = 0ull; s_rem = PRE_TOPN; }
    for (int pass = 0; pass < 8; ++pass) {
        int shift = 56 - pass * 8;
        hist[tid] = 0;
        __syncthreads();
        u64 pmask = pass ? (~0ull << (shift + 8)) : 0ull;
        u64 pref = s_prefix;
        for (int i = tid; i < NSC; i += 256) {
            u64 v = sb[i];
            if ((v & pmask) == pref) atomicAdd(&hist[(uint32_t)(v >> shift) & 0xFFu], 1u);
        }
        __syncthreads();
        if (tid == 0) {
            uint32_t rem = s_rem, cum = 0;
            int b = 255;
            for (; b > 0; --b) {
                if (cum + hist[b] >= rem) break;
                cum += hist[b];
            }
            s_prefix = pref | ((u64)(uint32_t)b << shift);
            s_rem = rem - cum;
        }
        __syncthreads();
    }
    if (tid == 0) Tsel[img] = s_prefix;
}

// ---- compact >=T, exact bitonic sort desc by (score, -idx), gather
__global__ __launch_bounds__(1024) void sort_gather(const double* __restrict__ dscores,
                                                    const double4* __restrict__ dprops,
                                                    const u64* __restrict__ Tsel,
                                                    double4* __restrict__ dboxes) {
    const int img = blockIdx.x;
    const int tid = threadIdx.x;
    __shared__ u64 skey[4096];
    __shared__ unsigned short sidx[4096];
    __shared__ int cnt;
    if (tid == 0) cnt = 0;
    for (int i = tid; i < 4096; i += 1024) { skey[i] = 0ull; sidx[i] = 0xFFFF; }
    __syncthreads();
    const u64 T = Tsel[img];
    const u64* sb = (const u64*)(dscores + (size_t)img * NSC);
    for (int i = tid; i < NSC; i += 1024) {
        u64 v = sb[i];
        if (v >= T) {
            int p = atomicAdd(&cnt, 1);
            if (p < 4096) { skey[p] = v; sidx[p] = (unsigned short)i; }
        }
    }
    __syncthreads();
    for (int k = 2; k <= 4096; k <<= 1) {
        for (int j = k >> 1; j > 0; j >>= 1) {
            for (int i = tid; i < 4096; i += 1024) {
                int ixj = i ^ j;
                if (ixj > i) {
                    u64 ka = skey[i], kb = skey[ixj];
                    unsigned short ia = sidx[i], ib = sidx[ixj];
                    bool aw = (ka < kb) || (ka == kb && ia > ib);
                    bool up = (i & k) == 0;
                    if (up ? aw : !aw) {
                        skey[i] = kb; skey[ixj] = ka;
                        sidx[i] = ib; sidx[ixj] = ia;
                    }
                }
            }
            __syncthreads();
        }
    }
    for (int t = tid; t < PRE_TOPN; t += 1024) {
        unsigned int idx = sidx[t];
        dboxes[(size_t)img * PRE_TOPN + t] = dprops[(size_t)img * NSC + idx];
    }
}

// ---- suppression bitmask (fp64 IoU): mask[i] bit j = IoU>0.7 && j>i
__global__ __launch_bounds__(256) void iou_mask_kernel(const double4* __restrict__ dboxes,
                                                       u64* __restrict__ mask) {
    const int tid = threadIdx.x;
    const int ib = blockIdx.x;
    const int img = blockIdx.y;
    const int i = ib * 64 + (tid >> 2);
    if (i >= PRE_TOPN) return;
    const double4 bi = dboxes[(size_t)img * PRE_TOPN + i];
    const double ai = (bi.z - bi.x) * (bi.w - bi.y);
    for (int w = (tid & 3); w < NWORDS; w += 4) {
        const int jbase = w * 64;
        u64 m = 0;
        if (jbase + 63 > i) {
            const int jmax = min(64, PRE_TOPN - jbase);
            for (int b = 0; b < jmax; ++b) {
                int j = jbase + b;
                if (j > i) {
                    double4 bj = dboxes[(size_t)img * PRE_TOPN + j];
                    double aj = (bj.z - bj.x) * (bj.w - bj.y);
                    double ltx = fmax(bi.x, bj.x), lty = fmax(bi.y, bj.y);
                    double rbx = fmin(bi.z, bj.z), rby = fmin(bi.w, bj.w);
                    double iw = fmax(rbx - ltx, 0.0), ih = fmax(rby - lty, 0.0);
                    double inter = iw * ih;
                    double iou = inter / (ai + aj - inter + 1e-9);
                    if (iou > 0.7) m |= (1ull << b);
                }
            }
        }
        mask[((size_t)img * PRE_TOPN + i) * MSTRIDE + w] = m;
    }
}

// ---- greedy walk, register-resident bitmap + ffs skip-scan (1 wave / image)
// Lane w owns removed-word w. Only KEPT indices do work; suppressed are skipped.
// Greedy ascending order identical to the serial reference walk.
__global__ __launch_bounds__(64) void nms_walk(const double4* __restrict__ dboxes,
                                               const u64* __restrict__ mask,
                                               float4* __restrict__ outb) {
    const int img = blockIdx.x;
    const int lane = threadIdx.x;
    __shared__ short kept[POST_TOPN];
    u64 removed = 0ull;
    int nk = 0;
    for (int w = 0; w < NWORDS && nk < POST_TOPN; ++w) {
        u64 freeb = ~__shfl(removed, w);
        if (w == NWORDS - 1)
            freeb &= (1ull << (PRE_TOPN - (NWORDS - 1) * 64)) - 1;  // 56 valid bits
        while (freeb != 0ull && nk < POST_TOPN) {
            int b = __ffsll((unsigned long long)freeb) - 1;
            int i = w * 64 + b;
            if (lane == 0) kept[nk] = (short)i;
            ++nk;
            u64 m = (lane < NWORDS)
                        ? mask[((size_t)img * PRE_TOPN + i) * MSTRIDE + lane]
                        : 0ull;
            removed |= m;
            // clear processed low bits, then drop newly suppressed bits of word w
            u64 hi = (b == 63) ? 0ull : (~0ull << (b + 1));
            freeb &= hi;
            freeb &= ~__shfl(removed, w);
        }
    }
    __syncthreads();
    const int n = nk;
    for (int r = lane; r < POST_TOPN; r += 64) {
        float4 v = make_float4(0.f, 0.f, 0.f, 0.f);
        if (r < n) {
            double4 d = dboxes[(size_t)img * PRE_TOPN + kept[r]];
            v = make_float4((float)d.x, (float)d.y, (float)d.z, (float)d.w);
        }
        outb[img * POST_TOPN + r] = v;
    }
}

extern "C" void kernel_launch(void* const* d_in, const int* in_sizes, int n_in,
                              void* d_out, int out_size, void* d_ws, size_t ws_size,
                              hipStream_t stream) {
    const float* x = (const float*)d_in[0];
    const float* im_size = (const float*)d_in[1];
    const float* Wconv = (const float*)d_in[2];
    const float* bconv = (const float*)d_in[3];
    const float* Wreg = (const float*)d_in[4];
    const float* breg = (const float*)d_in[5];
    const float* Wcls = (const float*)d_in[6];
    const float* bcls = (const float*)d_in[7];

    float* outf = (float*)d_out;
    float4* out_boxes = (float4*)outf;                               // 8*300*4
    float* out_scores = outf + NIMG * POST_TOPN * 4;                 // 8*36864
    float4* out_props = (float4*)(out_scores + (size_t)NIMG * NSC);  // 8*36864*4

    char* ws = (char*)d_ws;
    const size_t WT_OFF = 0;                                         // Wtf: 8*4608*80 f32
    const size_t WH_OFF = WT_OFF + (size_t)8 * 4608 * WROWF * 4;
    const size_t TS_OFF = WH_OFF + (size_t)512 * 64 * 4;
    const size_t VAR_OFF = TS_OFF + 64;
    const size_t DS_OFF = (VAR_OFF + 4 + 255) & ~(size_t)255;
    const size_t DP_OFF = DS_OFF + (size_t)NIMG * NSC * 8;
    const size_t DB_OFF = DP_OFF + (size_t)NIMG * NSC * 32;
    const size_t MK_OFF = DB_OFF + (size_t)NIMG * PRE_TOPN * 32;
    const size_t CV_OFF = (MK_OFF + (size_t)NIMG * PRE_TOPN * MSTRIDE * 8 + 255) & ~(size_t)255;

    float* Wtf = (float*)(ws + WT_OFF);
    float* Wh = (float*)(ws + WH_OFF);
    u64* Tsel = (u64*)(ws + TS_OFF);
    int* variant = (int*)(ws + VAR_OFF);
    double* dscores = (double*)(ws + DS_OFF);
    double4* dprops = (double4*)(ws + DP_OFF);
    double4* dboxes = (double4*)(ws + DB_OFF);
    u64* mask = (u64*)(ws + MK_OFF);
    double* convb = (double*)(ws + CV_OFF);

    const size_t per_img = (size_t)COUT * NPOS * 8;
    int CH = 1;
    if (ws_size > CV_OFF + per_img) {
        size_t avail = (ws_size - CV_OFF) / per_img;
        CH = (int)(avail > 8 ? 8 : avail);
        if (CH < 1) CH = 1;
    }

    transpose_wconv_f32<<<dim3(144, 16), 256, 0, stream>>>(Wconv, Wtf);
    build_wheads<<<128, 256, 0, stream>>>(Wreg, Wcls, Wh);
    mfma_probe<<<1, 64, 0, stream>>>(variant);

    for (int base = 0; base < NIMG; base += CH) {
        int n = NIMG - base;
        if (n > CH) n = CH;
        conv_mfma<<<dim3(8, 64, n), 512, 0, stream>>>(x, Wtf, bconv, convb, variant, base);
        conv_valu<<<dim3(8, 64, n), 256, 0, stream>>>(x, Wtf, bconv, convb, variant, base);
        heads_kernel<<<dim3(64, n), 256, 0, stream>>>(convb, Wh, breg, bcls, im_size,
                                                      out_scores, out_props,
                                                      dscores, dprops, base);
    }
    topk_select<<<NIMG, 256, 0, stream>>>(dscores, Tsel);
    sort_gather<<<NIMG, 1024, 0, stream>>>(dscores, dprops, Tsel, dboxes);
    iou_mask_kernel<<<dim3(NWORDS, NIMG), 256, 0, stream>>>(dboxes, mask);
    nms_walk<<<NIMG, 64, 0, stream>>>(dboxes, mask, out_boxes);
}